// Round 4
// baseline (263.527 us; speedup 1.0000x reference)
//
#include <hip/hip_runtime.h>
#include <hip/hip_bf16.h>
#include <math.h>

typedef __bf16 bf16_t;
typedef __attribute__((ext_vector_type(2))) __bf16 bf16x2;
typedef __attribute__((ext_vector_type(4))) __bf16 bf16x4;
typedef __attribute__((ext_vector_type(8))) __bf16 bf16x8;
typedef __attribute__((ext_vector_type(4))) float f32x4;

#define BATCH  2
#define SEQ    2048
#define DMODEL 1024
#define NHEADS 16
#define DK     64

typedef const __attribute__((address_space(1))) void* gas_t;
typedef __attribute__((address_space(3))) void* las_t;

#define X_N (BATCH * SEQ * DMODEL)        // 4,194,304
#define W_N (3 * DMODEL * DMODEL)         // 3,145,728
#define O_N (DMODEL * DMODEL)             // 1,048,576

__global__ __launch_bounds__(256) void convert_kernel(
    const float* __restrict__ x, const float* __restrict__ w, const float* __restrict__ o,
    bf16_t* __restrict__ xb, bf16_t* __restrict__ wb, bf16_t* __restrict__ ob)
{
    const int gid = blockIdx.x * 256 + threadIdx.x;   // 1,048,576 threads
    const float* src; bf16_t* dst; int base = gid * 8;
    if (base < X_N)                { src = x; dst = xb; }
    else if (base < X_N + W_N)     { src = w; dst = wb; base -= X_N; }
    else                           { src = o; dst = ob; base -= X_N + W_N; }
    const f32x4 lo = *(const f32x4*)(src + base);
    const f32x4 hi = *(const f32x4*)(src + base + 4);
    bf16x8 r;
    r[0] = (bf16_t)lo[0]; r[1] = (bf16_t)lo[1]; r[2] = (bf16_t)lo[2]; r[3] = (bf16_t)lo[3];
    r[4] = (bf16_t)hi[0]; r[5] = (bf16_t)hi[1]; r[6] = (bf16_t)hi[2]; r[7] = (bf16_t)hi[3];
    *(bf16x8*)(dst + base) = r;
}

// ---------------------------------------------------------------------------
// m97-style 128x128 GEMM body (qkv only).
// ---------------------------------------------------------------------------
__device__ __forceinline__ void gemm128_body(
    const bf16_t* __restrict__ A, const bf16_t* __restrict__ B,
    int rowBase, int colBase, bf16_t* ldsA, bf16_t* ldsB, f32x4 acc[4][4])
{
    const int tid  = threadIdx.x;
    const int lane = tid & 63;
    const int l15  = lane & 15, quad = lane >> 4;
    const int qr   = ((tid >> 6) >> 1) * 64;
    const int qc   = ((tid >> 6) & 1) * 64;

    const int c0 = tid, c1 = tid + 256;
    const int r0 = c0 >> 2, kc0 = (c0 & 3) * 8;
    const int r1 = c1 >> 2, kc1 = (c1 & 3) * 8;
    const bf16_t* ga0 = A + (size_t)(rowBase + r0) * DMODEL + kc0;
    const bf16_t* ga1 = A + (size_t)(rowBase + r1) * DMODEL + kc1;
    const bf16_t* gb0 = B + (size_t)(colBase + r0) * DMODEL + kc0;
    const bf16_t* gb1 = B + (size_t)(colBase + r1) * DMODEL + kc1;

    for (int k0 = 0; k0 < DMODEL; k0 += 32) {
        __syncthreads();
        __builtin_amdgcn_global_load_lds((gas_t)(ga0 + k0), (las_t)(ldsA + c0 * 8), 16, 0, 0);
        __builtin_amdgcn_global_load_lds((gas_t)(ga1 + k0), (las_t)(ldsA + c1 * 8), 16, 0, 0);
        __builtin_amdgcn_global_load_lds((gas_t)(gb0 + k0), (las_t)(ldsB + c0 * 8), 16, 0, 0);
        __builtin_amdgcn_global_load_lds((gas_t)(gb1 + k0), (las_t)(ldsB + c1 * 8), 16, 0, 0);
        __syncthreads();

        bf16x8 af[4], bfr[4];
#pragma unroll
        for (int i = 0; i < 4; ++i)
            af[i] = *(const bf16x8*)&ldsA[(qr + i * 16 + l15) * 32 + quad * 8];
#pragma unroll
        for (int j = 0; j < 4; ++j)
            bfr[j] = *(const bf16x8*)&ldsB[(qc + j * 16 + l15) * 32 + quad * 8];
#pragma unroll
        for (int i = 0; i < 4; ++i)
#pragma unroll
            for (int j = 0; j < 4; ++j)
                acc[i][j] = __builtin_amdgcn_mfma_f32_16x16x32_bf16(af[i], bfr[j], acc[i][j], 0, 0, 0);
    }
}

// ---------------------------------------------------------------------------
// QKV GEMM with fused RoPE. V is written TRANSPOSED per head with the 64-key
// tile permutation pos(k) = ((k&15)<<2)|(k>>4) — the same permutation the
// attention P-store uses, so PV fragment loads become contiguous bf16x8.
// ---------------------------------------------------------------------------
__global__ __launch_bounds__(256) void qkv_gemm_kernel(
    const bf16_t* __restrict__ x, const bf16_t* __restrict__ w,
    const int* __restrict__ pos,
    bf16_t* __restrict__ qo, bf16_t* __restrict__ ko, bf16_t* __restrict__ vt)
{
    __shared__ bf16_t ldsA[128 * 32];
    __shared__ bf16_t ldsB[128 * 32];
    const int rowBase = blockIdx.y * 128;
    const int colBase = blockIdx.x * 128;
    f32x4 acc[4][4] = {};
    gemm128_body(x, w, rowBase, colBase, ldsA, ldsB, acc);

    const int lane = threadIdx.x & 63;
    const int l15 = lane & 15, quad = lane >> 4;
    const int qr = ((threadIdx.x >> 6) >> 1) * 64;
    const int qc = ((threadIdx.x >> 6) & 1) * 64;
#pragma unroll
    for (int j = 0; j < 4; ++j) {
        const int col  = colBase + qc + j * 16 + l15;
        const int part = col >> 10;             // wave-uniform
        const int h    = (col & 1023) >> 6;
        const int d    = col & 63;
        bf16_t* op = (part == 0) ? qo : (part == 1) ? ko : vt;
        if (part < 2) {
            const float invf  = exp2f(-(float)(d >> 1) * 0.4152410118609203f);
            const float psign = (d & 1) ? 1.f : -1.f;
#pragma unroll
            for (int i = 0; i < 4; ++i) {
#pragma unroll
                for (int r = 0; r < 4; ++r) {
                    const int m = rowBase + qr + i * 16 + quad * 4 + r;
                    const int b = m >> 11;
                    const int s = m & (SEQ - 1);
                    const float ang = (float)pos[s] * invf;
                    const float sn_ = __sinf(ang);
                    const float c_  = __cosf(ang);
                    const float v = acc[i][j][r];
                    const float p = __shfl_xor(v, 1);
                    const float res = fmaf(p, psign * sn_, v * c_);
                    op[((size_t)(b * NHEADS + h) * SEQ + s) * DK + d] = (bf16_t)res;
                }
            }
        } else {
            // V^T permuted store: VT[bh][d][(s&~63) | pos(s&63)]
#pragma unroll
            for (int i = 0; i < 4; ++i) {
#pragma unroll
                for (int r = 0; r < 4; ++r) {
                    const int m = rowBase + qr + i * 16 + quad * 4 + r;
                    const int b = m >> 11;
                    const int s = m & (SEQ - 1);
                    const int sp = (s & ~63) | ((s & 15) << 2) | ((s >> 4) & 3);
                    op[(size_t)(b * NHEADS + h) * SEQ * DK + (size_t)d * SEQ + sp]
                        = (bf16_t)acc[i][j][r];
                }
            }
        }
    }
}

// ---------------------------------------------------------------------------
// Output GEMM: 128x64 tiles -> grid 512 blocks (2/CU).
// ---------------------------------------------------------------------------
__global__ __launch_bounds__(256) void out_gemm_kernel(
    const bf16_t* __restrict__ a, const bf16_t* __restrict__ w, float* __restrict__ out)
{
    __shared__ bf16_t ldsA[128 * 32];
    __shared__ bf16_t ldsB[64 * 32];
    const int tid  = threadIdx.x;
    const int lane = tid & 63;
    const int l15  = lane & 15, quad = lane >> 4;
    const int wv   = tid >> 6;
    const int rowBase = blockIdx.y * 128;
    const int colBase = blockIdx.x * 64;

    const int c0 = tid, c1 = tid + 256;
    const bf16_t* ga0 = a + (size_t)(rowBase + (c0 >> 2)) * DMODEL + (c0 & 3) * 8;
    const bf16_t* ga1 = a + (size_t)(rowBase + (c1 >> 2)) * DMODEL + (c1 & 3) * 8;
    const bf16_t* gb0 = w + (size_t)(colBase + (tid >> 2)) * DMODEL + (tid & 3) * 8;

    f32x4 acc[2][4] = {};
    for (int k0 = 0; k0 < DMODEL; k0 += 32) {
        __syncthreads();
        __builtin_amdgcn_global_load_lds((gas_t)(ga0 + k0), (las_t)(ldsA + c0 * 8), 16, 0, 0);
        __builtin_amdgcn_global_load_lds((gas_t)(ga1 + k0), (las_t)(ldsA + c1 * 8), 16, 0, 0);
        __builtin_amdgcn_global_load_lds((gas_t)(gb0 + k0), (las_t)(ldsB + tid * 8), 16, 0, 0);
        __syncthreads();

        bf16x8 af[2], bfr[4];
#pragma unroll
        for (int i = 0; i < 2; ++i)
            af[i] = *(const bf16x8*)&ldsA[(wv * 32 + i * 16 + l15) * 32 + quad * 8];
#pragma unroll
        for (int j = 0; j < 4; ++j)
            bfr[j] = *(const bf16x8*)&ldsB[(j * 16 + l15) * 32 + quad * 8];
#pragma unroll
        for (int i = 0; i < 2; ++i)
#pragma unroll
            for (int j = 0; j < 4; ++j)
                acc[i][j] = __builtin_amdgcn_mfma_f32_16x16x32_bf16(af[i], bfr[j], acc[i][j], 0, 0, 0);
    }
#pragma unroll
    for (int i = 0; i < 2; ++i) {
#pragma unroll
        for (int r = 0; r < 4; ++r) {
            const int m = rowBase + wv * 32 + i * 16 + quad * 4 + r;
#pragma unroll
            for (int j = 0; j < 4; ++j)
                out[(size_t)m * DMODEL + colBase + j * 16 + l15] = acc[i][j][r];
        }
    }
}

// ---------------------------------------------------------------------------
// Split-K flash attention v10: v8 loop verbatim, 8-wave (512-thread) blocks.
//   - grid 1024 x 512thr = 4 blocks/CU x 8 waves = 32 waves/CU (v8 had 16):
//     2x latency hiding, per-wave critical path 9 -> 5 tiles.
//   - pair (w0=p, w1=63-p) owns 33 tiles; chunks {5,4,4,4,4,4,4,4}.
//   - XCD-local bh decode kept (FETCH 129 -> 12.5 MB proven in R1).
//   - epilogue: v8's proven global-atomic accumulate (v9's flat-atomic LDS
//     reduction was a 16 us regression — reverted).
// ---------------------------------------------------------------------------
__device__ __forceinline__ void attn_segment(
    const bf16_t* __restrict__ Q, const bf16_t* __restrict__ K,
    const bf16_t* __restrict__ VT,
    float* __restrict__ OAcc, float* __restrict__ LAcc,
    bf16_t* __restrict__ Pw, size_t hb, int bh,
    int w, int kb_lo, int kb_hi, int lane)
{
    if (kb_lo >= kb_hi) return;
    const int l15 = lane & 15, quad = lane >> 4;
    const int q0 = w * 32;
    const int kbLast = w >> 1;                 // diagonal tile of this q-wave

    // Q fragments (queries q0+16f .. +15), pre-scaled by 1/8
    bf16x8 aq0[2], aq1[2];
#pragma unroll
    for (int f = 0; f < 2; ++f) {
        const bf16_t* qrow = Q + hb + (size_t)(q0 + 16 * f + l15) * DK + quad * 8;
        aq0[f] = *(const bf16x8*)qrow;
        aq1[f] = *(const bf16x8*)(qrow + 32);
#pragma unroll
        for (int i = 0; i < 8; ++i) {
            aq0[f][i] = (bf16_t)((float)aq0[f][i] * 0.125f);
            aq1[f][i] = (bf16_t)((float)aq1[f][i] * 0.125f);
        }
    }

    f32x4 oacc[2][4] = {};
    float lsum[2][4] = {};

    const bf16_t* kg0 = K  + hb + (size_t)l15 * DK  + quad * 8;
    const bf16_t* vg0 = VT + hb + (size_t)l15 * SEQ + quad * 8;

    // ---- prologue: K[kb_lo] fragments ----
    bf16x8 kf0[4], kf1[4];
    {
        const bf16_t* kg = kg0 + (size_t)kb_lo * (64 * DK);
#pragma unroll
        for (int c = 0; c < 4; ++c) {
            kf0[c] = *(const bf16x8*)(kg + c * 16 * DK);
            kf1[c] = *(const bf16x8*)(kg + c * 16 * DK + 32);
        }
    }

    for (int kb = kb_lo; kb < kb_hi; ++kb) {
        // ---- V[kb] loads first: consumed only at the PV MFMAs below ----
        bf16x8 bv0[4], bv1[4];
        {
            const bf16_t* vg = vg0 + kb * 64;
#pragma unroll
            for (int t = 0; t < 4; ++t) {
                bv0[t] = *(const bf16x8*)(vg + (size_t)t * 16 * SEQ);
                bv1[t] = *(const bf16x8*)(vg + (size_t)t * 16 * SEQ + 32);
            }
        }
        const bool needmask = (kb == kbLast);  // wave-uniform

        // ---- f=0 QK scores ----
        f32x4 sc0[4];
#pragma unroll
        for (int c = 0; c < 4; ++c) {
            f32x4 z = {};
            z = __builtin_amdgcn_mfma_f32_16x16x32_bf16(aq0[0], kf0[c], z, 0, 0, 0);
            z = __builtin_amdgcn_mfma_f32_16x16x32_bf16(aq1[0], kf1[c], z, 0, 0, 0);
            sc0[c] = z;
        }
        // ---- f=0 exp + packed P store (overlaps f=1 QK issue) ----
#pragma unroll
        for (int r = 0; r < 4; ++r) {
            bf16x4 pr;
#pragma unroll
            for (int c = 0; c < 4; ++c) {
                float s = sc0[c][r];
                if (needmask) {
                    const int key = kb * 64 + c * 16 + l15;
                    const int qa  = q0 + quad * 4 + r;
                    s = (key <= qa) ? s : -INFINITY;
                }
                const float p = __expf(s - 8.0f);
                lsum[0][r] += p;
                pr[c] = (bf16_t)p;
            }
            *(bf16x4*)&Pw[(quad * 4 + r) * 72 + l15 * 4] = pr;
        }

        // ---- f=1 QK scores (last use of kf) ----
        f32x4 sc1[4];
#pragma unroll
        for (int c = 0; c < 4; ++c) {
            f32x4 z = {};
            z = __builtin_amdgcn_mfma_f32_16x16x32_bf16(aq0[1], kf0[c], z, 0, 0, 0);
            z = __builtin_amdgcn_mfma_f32_16x16x32_bf16(aq1[1], kf1[c], z, 0, 0, 0);
            sc1[c] = z;
        }
        // ---- prefetch K[kb+1] in place (kf dead; +1 overread stays in ws) ----
        {
            const bf16_t* kg = kg0 + (size_t)(kb + 1) * (64 * DK);
#pragma unroll
            for (int c = 0; c < 4; ++c) {
                kf0[c] = *(const bf16x8*)(kg + c * 16 * DK);
                kf1[c] = *(const bf16x8*)(kg + c * 16 * DK + 32);
            }
        }
        // ---- f=1 exp + packed P store ----
#pragma unroll
        for (int r = 0; r < 4; ++r) {
            bf16x4 pr;
#pragma unroll
            for (int c = 0; c < 4; ++c) {
                float s = sc1[c][r];
                if (needmask) {
                    const int key = kb * 64 + c * 16 + l15;
                    const int qa  = q0 + 16 + quad * 4 + r;
                    s = (key <= qa) ? s : -INFINITY;
                }
                const float p = __expf(s - 8.0f);
                lsum[1][r] += p;
                pr[c] = (bf16_t)p;
            }
            *(bf16x4*)&Pw[(16 + quad * 4 + r) * 72 + l15 * 4] = pr;
        }
        asm volatile("s_waitcnt lgkmcnt(0)" ::: "memory");  // wave-private LDS RAW

        bf16x8 ap0[2], ap1[2];
#pragma unroll
        for (int f = 0; f < 2; ++f) {
            ap0[f] = *(const bf16x8*)&Pw[(16 * f + l15) * 72 + quad * 8];
            ap1[f] = *(const bf16x8*)&Pw[(16 * f + l15) * 72 + 32 + quad * 8];
        }

        // ---- O += P.V (V^T fragments direct from global) ----
#pragma unroll
        for (int t = 0; t < 4; ++t)
#pragma unroll
            for (int f = 0; f < 2; ++f) {
                oacc[f][t] = __builtin_amdgcn_mfma_f32_16x16x32_bf16(ap0[f], bv0[t], oacc[f][t], 0, 0, 0);
                oacc[f][t] = __builtin_amdgcn_mfma_f32_16x16x32_bf16(ap1[f], bv1[t], oacc[f][t], 0, 0, 0);
            }
    }

    // ---- flush: atomically accumulate (O, l) in fp32 ----
    const int b = bh >> 4, h = bh & 15;
#pragma unroll
    for (int f = 0; f < 2; ++f) {
#pragma unroll
        for (int r = 0; r < 4; ++r) {
            float s = lsum[f][r];
            s += __shfl_xor(s, 1);
            s += __shfl_xor(s, 2);
            s += __shfl_xor(s, 4);
            s += __shfl_xor(s, 8);
            if (l15 == 0)
                unsafeAtomicAdd(&LAcc[(size_t)bh * SEQ + (q0 + 16 * f + quad * 4 + r)], s);
        }
#pragma unroll
        for (int t = 0; t < 4; ++t)
#pragma unroll
            for (int r = 0; r < 4; ++r) {
                const int qa = q0 + 16 * f + quad * 4 + r;
                unsafeAtomicAdd(&OAcc[(size_t)(b * SEQ + qa) * DMODEL + h * 64 + t * 16 + l15],
                                oacc[f][t][r]);
            }
    }
}

__global__ __launch_bounds__(512) void attn_kernel(
    const bf16_t* __restrict__ Q, const bf16_t* __restrict__ K,
    const bf16_t* __restrict__ VT,
    float* __restrict__ OAcc, float* __restrict__ LAcc)
{
    __shared__ bf16_t Pb[8][32 * 72];            // per-wave P, 36,864 B total
    // XCD-local decode: XCD = linear%8 = bh%8 -> 4 heads per XCD (2 MiB K+V)
    const int bh   = blockIdx.x & 31;            // 0..31
    const int p    = blockIdx.x >> 5;            // symmetric pair 0..31
    const int wave = threadIdx.x >> 6, lane = threadIdx.x & 63;
    const size_t hb = (size_t)bh * SEQ * DK;

    // pair (w0=p, w1=63-p) owns 33 tiles; chunks {5,4,4,4,4,4,4,4}
    const int cs = (wave == 0) ? 0 : 5 + (wave - 1) * 4;
    const int ce = (wave == 0) ? 5 : cs + 4;
    const int w0 = p, w1 = 63 - p;
    const int t1 = (w0 >> 1) + 1;                // tiles belonging to w0

    attn_segment(Q, K, VT, OAcc, LAcc, Pb[wave], hb, bh,
                 w0, cs, min(ce, t1), lane);
    attn_segment(Q, K, VT, OAcc, LAcc, Pb[wave], hb, bh,
                 w1, max(cs, t1) - t1, ce - t1, lane);
}

// ---------------------------------------------------------------------------
// Normalize: AO_bf16 = OAcc / LAcc  (4 elems/thread).
// ---------------------------------------------------------------------------
__global__ __launch_bounds__(256) void norm_kernel(
    const float* __restrict__ OAcc, const float* __restrict__ LAcc,
    bf16_t* __restrict__ AO)
{
    const int gid = blockIdx.x * 256 + threadIdx.x;   // 1,048,576 threads
    const int m  = gid >> 8;
    const int c4 = (gid & 255) * 4;
    const int h  = c4 >> 6;
    const int b  = m >> 11;
    const int s  = m & (SEQ - 1);
    const float inv = 1.0f / LAcc[(size_t)(b * NHEADS + h) * SEQ + s];
    const f32x4 o = *(const f32x4*)&OAcc[(size_t)m * DMODEL + c4];
    bf16x4 r;
    r[0] = (bf16_t)(o[0] * inv); r[1] = (bf16_t)(o[1] * inv);
    r[2] = (bf16_t)(o[2] * inv); r[3] = (bf16_t)(o[3] * inv);
    *(bf16x4*)&AO[(size_t)m * DMODEL + c4] = r;
}

extern "C" void kernel_launch(void* const* d_in, const int* in_sizes, int n_in,
                              void* d_out, int out_size, void* d_ws, size_t ws_size,
                              hipStream_t stream) {
    (void)in_sizes; (void)n_in; (void)out_size; (void)ws_size;
    const float* x    = (const float*)d_in[0];
    const int*   pos  = (const int*)d_in[1];
    const float* qkvw = (const float*)d_in[2];
    const float* ow   = (const float*)d_in[3];
    float* out = (float*)d_out;

    const size_t HEAD_ELEMS = (size_t)BATCH * NHEADS * SEQ * DK;  // 4,194,304
    bf16_t* Qw  = (bf16_t*)d_ws;              // 8 MiB
    bf16_t* Kw  = Qw + HEAD_ELEMS;            // 8 MiB
    bf16_t* Vt  = Kw + HEAD_ELEMS;            // 8 MiB (transposed+permuted V)
    bf16_t* AO  = Vt + HEAD_ELEMS;            // 8 MiB — aliased with xb (disjoint live ranges)
    bf16_t* xb  = AO;
    bf16_t* wb  = AO + X_N;                   // 6 MiB
    bf16_t* ob  = wb + W_N;                   // 2 MiB
    float*  OAcc = (float*)(ob + O_N);        // 16 MiB fp32
    float*  LAcc = OAcc + (size_t)X_N;        // 256 KiB fp32  (total ~56.25 MiB)

    // 0) zero the attention accumulators
    hipMemsetAsync(OAcc, 0, (size_t)X_N * 4 + (size_t)BATCH * NHEADS * SEQ * 4, stream);
    // 1) fp32 -> bf16 for x, qkv_proj, o_proj
    convert_kernel<<<dim3(4096), 256, 0, stream>>>(x, qkvw, ow, xb, wb, ob);
    // 2) QKV projection + fused RoPE -> head-major Q/K, transposed-permuted V
    qkv_gemm_kernel<<<dim3(24, 32), 256, 0, stream>>>(xb, wb, pos, Qw, Kw, Vt);
    // 3) XCD-local flash attention, 8 waves/block (32 waves/CU) -> fp32 partials
    attn_kernel<<<dim3(1024), 512, 0, stream>>>(Qw, Kw, Vt, OAcc, LAcc);
    // 4) normalize -> AO bf16
    norm_kernel<<<dim3(4096), 256, 0, stream>>>(OAcc, LAcc, AO);
    // 5) output projection (128x64 tiles, 512 blocks) -> fp32 d_out
    out_gemm_kernel<<<dim3(16, 32), 256, 0, stream>>>(AO, ob, out);
}

// Round 5
// 208.018 us; speedup vs baseline: 1.2668x; 1.2668x over previous
//
#include <hip/hip_runtime.h>
#include <hip/hip_bf16.h>
#include <math.h>

typedef __bf16 bf16_t;
typedef __attribute__((ext_vector_type(2))) __bf16 bf16x2;
typedef __attribute__((ext_vector_type(4))) __bf16 bf16x4;
typedef __attribute__((ext_vector_type(8))) __bf16 bf16x8;
typedef __attribute__((ext_vector_type(4))) float f32x4;

#define BATCH  2
#define SEQ    2048
#define DMODEL 1024
#define NHEADS 16
#define DK     64

typedef const __attribute__((address_space(1))) void* gas_t;
typedef __attribute__((address_space(3))) void* las_t;

#define X_N (BATCH * SEQ * DMODEL)        // 4,194,304
#define W_N (3 * DMODEL * DMODEL)         // 3,145,728
#define O_N (DMODEL * DMODEL)             // 1,048,576

__global__ __launch_bounds__(256) void convert_kernel(
    const float* __restrict__ x, const float* __restrict__ w, const float* __restrict__ o,
    bf16_t* __restrict__ xb, bf16_t* __restrict__ wb, bf16_t* __restrict__ ob)
{
    const int gid = blockIdx.x * 256 + threadIdx.x;   // 1,048,576 threads
    const float* src; bf16_t* dst; int base = gid * 8;
    if (base < X_N)                { src = x; dst = xb; }
    else if (base < X_N + W_N)     { src = w; dst = wb; base -= X_N; }
    else                           { src = o; dst = ob; base -= X_N + W_N; }
    const f32x4 lo = *(const f32x4*)(src + base);
    const f32x4 hi = *(const f32x4*)(src + base + 4);
    bf16x8 r;
    r[0] = (bf16_t)lo[0]; r[1] = (bf16_t)lo[1]; r[2] = (bf16_t)lo[2]; r[3] = (bf16_t)lo[3];
    r[4] = (bf16_t)hi[0]; r[5] = (bf16_t)hi[1]; r[6] = (bf16_t)hi[2]; r[7] = (bf16_t)hi[3];
    *(bf16x8*)(dst + base) = r;
}

// ---------------------------------------------------------------------------
// m97-style 128x128 GEMM body (qkv only).
// ---------------------------------------------------------------------------
__device__ __forceinline__ void gemm128_body(
    const bf16_t* __restrict__ A, const bf16_t* __restrict__ B,
    int rowBase, int colBase, bf16_t* ldsA, bf16_t* ldsB, f32x4 acc[4][4])
{
    const int tid  = threadIdx.x;
    const int lane = tid & 63;
    const int l15  = lane & 15, quad = lane >> 4;
    const int qr   = ((tid >> 6) >> 1) * 64;
    const int qc   = ((tid >> 6) & 1) * 64;

    const int c0 = tid, c1 = tid + 256;
    const int r0 = c0 >> 2, kc0 = (c0 & 3) * 8;
    const int r1 = c1 >> 2, kc1 = (c1 & 3) * 8;
    const bf16_t* ga0 = A + (size_t)(rowBase + r0) * DMODEL + kc0;
    const bf16_t* ga1 = A + (size_t)(rowBase + r1) * DMODEL + kc1;
    const bf16_t* gb0 = B + (size_t)(colBase + r0) * DMODEL + kc0;
    const bf16_t* gb1 = B + (size_t)(colBase + r1) * DMODEL + kc1;

    for (int k0 = 0; k0 < DMODEL; k0 += 32) {
        __syncthreads();
        __builtin_amdgcn_global_load_lds((gas_t)(ga0 + k0), (las_t)(ldsA + c0 * 8), 16, 0, 0);
        __builtin_amdgcn_global_load_lds((gas_t)(ga1 + k0), (las_t)(ldsA + c1 * 8), 16, 0, 0);
        __builtin_amdgcn_global_load_lds((gas_t)(gb0 + k0), (las_t)(ldsB + c0 * 8), 16, 0, 0);
        __builtin_amdgcn_global_load_lds((gas_t)(gb1 + k0), (las_t)(ldsB + c1 * 8), 16, 0, 0);
        __syncthreads();

        bf16x8 af[4], bfr[4];
#pragma unroll
        for (int i = 0; i < 4; ++i)
            af[i] = *(const bf16x8*)&ldsA[(qr + i * 16 + l15) * 32 + quad * 8];
#pragma unroll
        for (int j = 0; j < 4; ++j)
            bfr[j] = *(const bf16x8*)&ldsB[(qc + j * 16 + l15) * 32 + quad * 8];
#pragma unroll
        for (int i = 0; i < 4; ++i)
#pragma unroll
            for (int j = 0; j < 4; ++j)
                acc[i][j] = __builtin_amdgcn_mfma_f32_16x16x32_bf16(af[i], bfr[j], acc[i][j], 0, 0, 0);
    }
}

// ---------------------------------------------------------------------------
// QKV GEMM with fused RoPE. V is written TRANSPOSED per head with the 64-key
// tile permutation pos(k) = ((k&15)<<2)|(k>>4) — the same permutation the
// attention P-store uses, so PV fragment loads become contiguous bf16x8.
// ---------------------------------------------------------------------------
__global__ __launch_bounds__(256) void qkv_gemm_kernel(
    const bf16_t* __restrict__ x, const bf16_t* __restrict__ w,
    const int* __restrict__ pos,
    bf16_t* __restrict__ qo, bf16_t* __restrict__ ko, bf16_t* __restrict__ vt)
{
    __shared__ bf16_t ldsA[128 * 32];
    __shared__ bf16_t ldsB[128 * 32];
    const int rowBase = blockIdx.y * 128;
    const int colBase = blockIdx.x * 128;
    f32x4 acc[4][4] = {};
    gemm128_body(x, w, rowBase, colBase, ldsA, ldsB, acc);

    const int lane = threadIdx.x & 63;
    const int l15 = lane & 15, quad = lane >> 4;
    const int qr = ((threadIdx.x >> 6) >> 1) * 64;
    const int qc = ((threadIdx.x >> 6) & 1) * 64;
#pragma unroll
    for (int j = 0; j < 4; ++j) {
        const int col  = colBase + qc + j * 16 + l15;
        const int part = col >> 10;             // wave-uniform
        const int h    = (col & 1023) >> 6;
        const int d    = col & 63;
        bf16_t* op = (part == 0) ? qo : (part == 1) ? ko : vt;
        if (part < 2) {
            const float invf  = exp2f(-(float)(d >> 1) * 0.4152410118609203f);
            const float psign = (d & 1) ? 1.f : -1.f;
#pragma unroll
            for (int i = 0; i < 4; ++i) {
#pragma unroll
                for (int r = 0; r < 4; ++r) {
                    const int m = rowBase + qr + i * 16 + quad * 4 + r;
                    const int b = m >> 11;
                    const int s = m & (SEQ - 1);
                    const float ang = (float)pos[s] * invf;
                    const float sn_ = __sinf(ang);
                    const float c_  = __cosf(ang);
                    const float v = acc[i][j][r];
                    const float p = __shfl_xor(v, 1);
                    const float res = fmaf(p, psign * sn_, v * c_);
                    op[((size_t)(b * NHEADS + h) * SEQ + s) * DK + d] = (bf16_t)res;
                }
            }
        } else {
            // V^T permuted store: VT[bh][d][(s&~63) | pos(s&63)]
#pragma unroll
            for (int i = 0; i < 4; ++i) {
#pragma unroll
                for (int r = 0; r < 4; ++r) {
                    const int m = rowBase + qr + i * 16 + quad * 4 + r;
                    const int b = m >> 11;
                    const int s = m & (SEQ - 1);
                    const int sp = (s & ~63) | ((s & 15) << 2) | ((s >> 4) & 3);
                    op[(size_t)(b * NHEADS + h) * SEQ * DK + (size_t)d * SEQ + sp]
                        = (bf16_t)acc[i][j][r];
                }
            }
        }
    }
}

// ---------------------------------------------------------------------------
// Output GEMM: 128x64 tiles -> grid 512 blocks (2/CU).
// ---------------------------------------------------------------------------
__global__ __launch_bounds__(256) void out_gemm_kernel(
    const bf16_t* __restrict__ a, const bf16_t* __restrict__ w, float* __restrict__ out)
{
    __shared__ bf16_t ldsA[128 * 32];
    __shared__ bf16_t ldsB[64 * 32];
    const int tid  = threadIdx.x;
    const int lane = tid & 63;
    const int l15  = lane & 15, quad = lane >> 4;
    const int wv   = tid >> 6;
    const int rowBase = blockIdx.y * 128;
    const int colBase = blockIdx.x * 64;

    const int c0 = tid, c1 = tid + 256;
    const bf16_t* ga0 = a + (size_t)(rowBase + (c0 >> 2)) * DMODEL + (c0 & 3) * 8;
    const bf16_t* ga1 = a + (size_t)(rowBase + (c1 >> 2)) * DMODEL + (c1 & 3) * 8;
    const bf16_t* gb0 = w + (size_t)(colBase + (tid >> 2)) * DMODEL + (tid & 3) * 8;

    f32x4 acc[2][4] = {};
    for (int k0 = 0; k0 < DMODEL; k0 += 32) {
        __syncthreads();
        __builtin_amdgcn_global_load_lds((gas_t)(ga0 + k0), (las_t)(ldsA + c0 * 8), 16, 0, 0);
        __builtin_amdgcn_global_load_lds((gas_t)(ga1 + k0), (las_t)(ldsA + c1 * 8), 16, 0, 0);
        __builtin_amdgcn_global_load_lds((gas_t)(gb0 + k0), (las_t)(ldsB + tid * 8), 16, 0, 0);
        __syncthreads();

        bf16x8 af[2], bfr[4];
#pragma unroll
        for (int i = 0; i < 2; ++i)
            af[i] = *(const bf16x8*)&ldsA[(wv * 32 + i * 16 + l15) * 32 + quad * 8];
#pragma unroll
        for (int j = 0; j < 4; ++j)
            bfr[j] = *(const bf16x8*)&ldsB[(j * 16 + l15) * 32 + quad * 8];
#pragma unroll
        for (int i = 0; i < 2; ++i)
#pragma unroll
            for (int j = 0; j < 4; ++j)
                acc[i][j] = __builtin_amdgcn_mfma_f32_16x16x32_bf16(af[i], bfr[j], acc[i][j], 0, 0, 0);
    }
#pragma unroll
    for (int i = 0; i < 2; ++i) {
#pragma unroll
        for (int r = 0; r < 4; ++r) {
            const int m = rowBase + wv * 32 + i * 16 + quad * 4 + r;
#pragma unroll
            for (int j = 0; j < 4; ++j)
                out[(size_t)m * DMODEL + colBase + j * 16 + l15] = acc[i][j][r];
        }
    }
}

// ---------------------------------------------------------------------------
// Flash attention v11: classic 128-query blocks, NO split-K, NO atomics.
//   - block (qb, bh): 4 waves x 32 queries; sweeps kb = 0..2qb+1 with K and V
//     tiles staged ONCE into LDS (double-buffered global_load_lds, shared by
//     all 4 waves) — removes the 4x-redundant per-wave scattered L2 loads.
//   - each wave owns its rows end-to-end: lsum complete in-wave -> fused
//     1/l normalize + direct AO bf16 write. OAcc/LAcc/memset/norm all gone
//     (43-77 MB of L3 atomic RMW + ~40 MB of downstream traffic).
//   - chunk-XOR swizzle (c ^= row&7, 16B chunks) on K/V tiles: staged with
//     pre-swizzled per-lane SOURCE + linear LDS dest (m173 pattern), read
//     back with the same XOR -> uniform 8-lanes/slot bank spread.
//   - balance: co-resident pair (j, j+8) -> (qb, 15-qb): 34 tiles per CU.
//   - inner math identical to v8 (QK pairing, exp(s-8), P roundtrip, PV).
// ---------------------------------------------------------------------------
__global__ __launch_bounds__(256) void attn_kernel(
    const bf16_t* __restrict__ Q, const bf16_t* __restrict__ K,
    const bf16_t* __restrict__ VT, bf16_t* __restrict__ AO)
{
    __shared__ bf16_t Kb[2][64 * 64];            // 16 KiB
    __shared__ bf16_t Vb[2][64 * 64];            // 16 KiB
    __shared__ bf16_t Pb[4][32 * 72];            // 18 KiB

    const int bh = blockIdx.x & 31;              // XCD = blk%8 = bh%8
    const int j  = blockIdx.x >> 5;              // 0..15
    const int qb = (j < 8) ? j : 23 - j;         // pair (j, j+8) -> (qb, 15-qb)
    const int nt = 2 * qb + 2;                   // causal tile count

    const int tid  = threadIdx.x;
    const int wave = tid >> 6, lane = tid & 63;
    const int l15  = lane & 15, quad = lane >> 4;
    const int q0   = qb * 128 + wave * 32;
    const size_t hb = (size_t)bh * SEQ * DK;

    // staging map: thread covers 16B chunks g = (wave*2+ii)*64 + lane;
    // r = g>>3 (tile row), c = g&7 (chunk); source chunk pre-swizzled c^(r&7)
    const int sr0 = wave * 16 + (lane >> 3);     // ii=0 row
    const int sc0 = ((lane & 7) ^ (sr0 & 7)) * 8;
    const int sr1 = sr0 + 8;                     // ii=1 row
    const int sc1 = ((lane & 7) ^ (sr1 & 7)) * 8;
    const int d0  = (wave * 2) * 512 + lane * 8;        // LDS elem offset ii=0
    const int d1  = (wave * 2 + 1) * 512 + lane * 8;    // ii=1

    // Q fragments (queries q0+16f..+15), pre-scaled by 1/8
    bf16x8 aq0[2], aq1[2];
#pragma unroll
    for (int f = 0; f < 2; ++f) {
        const bf16_t* qrow = Q + hb + (size_t)(q0 + 16 * f + l15) * DK + quad * 8;
        aq0[f] = *(const bf16x8*)qrow;
        aq1[f] = *(const bf16x8*)(qrow + 32);
#pragma unroll
        for (int i = 0; i < 8; ++i) {
            aq0[f][i] = (bf16_t)((float)aq0[f][i] * 0.125f);
            aq1[f][i] = (bf16_t)((float)aq1[f][i] * 0.125f);
        }
    }

    f32x4 oacc[2][4] = {};
    float lsum[2][4] = {};

    // ---- prologue: stage tile 0 into buf 0 ----
    __builtin_amdgcn_global_load_lds((gas_t)(K  + hb + (size_t)sr0 * DK + sc0),
                                     (las_t)(&Kb[0][d0]), 16, 0, 0);
    __builtin_amdgcn_global_load_lds((gas_t)(K  + hb + (size_t)sr1 * DK + sc1),
                                     (las_t)(&Kb[0][d1]), 16, 0, 0);
    __builtin_amdgcn_global_load_lds((gas_t)(VT + hb + (size_t)sr0 * SEQ + sc0),
                                     (las_t)(&Vb[0][d0]), 16, 0, 0);
    __builtin_amdgcn_global_load_lds((gas_t)(VT + hb + (size_t)sr1 * SEQ + sc1),
                                     (las_t)(&Vb[0][d1]), 16, 0, 0);
    __syncthreads();

    const int swA = (quad ^ (l15 & 7)) * 8;           // read-side XOR, chunks 0-3
    const int swB = ((4 + quad) ^ (l15 & 7)) * 8;     // chunks 4-7

    int buf = 0;
    for (int kb = 0; kb < nt; ++kb) {
        // ---- stage next tile into buf^1 (overlaps this tile's compute) ----
        if (kb + 1 < nt) {
            const bf16_t* kg = K  + hb + (size_t)(kb + 1) * 64 * DK;
            const bf16_t* vg = VT + hb + (kb + 1) * 64;
            bf16_t* kd = &Kb[buf ^ 1][0];
            bf16_t* vd = &Vb[buf ^ 1][0];
            __builtin_amdgcn_global_load_lds((gas_t)(kg + (size_t)sr0 * DK + sc0),
                                             (las_t)(kd + d0), 16, 0, 0);
            __builtin_amdgcn_global_load_lds((gas_t)(kg + (size_t)sr1 * DK + sc1),
                                             (las_t)(kd + d1), 16, 0, 0);
            __builtin_amdgcn_global_load_lds((gas_t)(vg + (size_t)sr0 * SEQ + sc0),
                                             (las_t)(vd + d0), 16, 0, 0);
            __builtin_amdgcn_global_load_lds((gas_t)(vg + (size_t)sr1 * SEQ + sc1),
                                             (las_t)(vd + d1), 16, 0, 0);
        }

        // ---- K/V fragments from shared LDS tiles ----
        bf16x8 kf0[4], kf1[4], bv0[4], bv1[4];
#pragma unroll
        for (int c = 0; c < 4; ++c) {
            kf0[c] = *(const bf16x8*)&Kb[buf][(c * 16 + l15) * 64 + swA];
            kf1[c] = *(const bf16x8*)&Kb[buf][(c * 16 + l15) * 64 + swB];
        }
#pragma unroll
        for (int t = 0; t < 4; ++t) {
            bv0[t] = *(const bf16x8*)&Vb[buf][(t * 16 + l15) * 64 + swA];
            bv1[t] = *(const bf16x8*)&Vb[buf][(t * 16 + l15) * 64 + swB];
        }

        const bool act0 = (kb * 64 <= q0 + 15);       // wave-uniform
        const bool act1 = (kb * 64 <= q0 + 31);
        const bool nm0  = (kb * 64 + 63 > q0);
        const bool nm1  = (kb * 64 + 63 > q0 + 16);

        if (act0) {
            f32x4 sc[4];
#pragma unroll
            for (int c = 0; c < 4; ++c) {
                f32x4 z = {};
                z = __builtin_amdgcn_mfma_f32_16x16x32_bf16(aq0[0], kf0[c], z, 0, 0, 0);
                z = __builtin_amdgcn_mfma_f32_16x16x32_bf16(aq1[0], kf1[c], z, 0, 0, 0);
                sc[c] = z;
            }
#pragma unroll
            for (int r = 0; r < 4; ++r) {
                bf16x4 pr;
#pragma unroll
                for (int c = 0; c < 4; ++c) {
                    float s = sc[c][r];
                    if (nm0) {
                        const int key = kb * 64 + c * 16 + l15;
                        const int qa  = q0 + quad * 4 + r;
                        s = (key <= qa) ? s : -INFINITY;
                    }
                    const float p = __expf(s - 8.0f);
                    lsum[0][r] += p;
                    pr[c] = (bf16_t)p;
                }
                *(bf16x4*)&Pb[wave][(quad * 4 + r) * 72 + l15 * 4] = pr;
            }
        }
        if (act1) {
            f32x4 sc[4];
#pragma unroll
            for (int c = 0; c < 4; ++c) {
                f32x4 z = {};
                z = __builtin_amdgcn_mfma_f32_16x16x32_bf16(aq0[1], kf0[c], z, 0, 0, 0);
                z = __builtin_amdgcn_mfma_f32_16x16x32_bf16(aq1[1], kf1[c], z, 0, 0, 0);
                sc[c] = z;
            }
#pragma unroll
            for (int r = 0; r < 4; ++r) {
                bf16x4 pr;
#pragma unroll
                for (int c = 0; c < 4; ++c) {
                    float s = sc[c][r];
                    if (nm1) {
                        const int key = kb * 64 + c * 16 + l15;
                        const int qa  = q0 + 16 + quad * 4 + r;
                        s = (key <= qa) ? s : -INFINITY;
                    }
                    const float p = __expf(s - 8.0f);
                    lsum[1][r] += p;
                    pr[c] = (bf16_t)p;
                }
                *(bf16x4*)&Pb[wave][(16 + quad * 4 + r) * 72 + l15 * 4] = pr;
            }
        }
        asm volatile("s_waitcnt lgkmcnt(0)" ::: "memory");  // wave-private LDS RAW

        if (act0) {
            const bf16x8 ap0 = *(const bf16x8*)&Pb[wave][l15 * 72 + quad * 8];
            const bf16x8 ap1 = *(const bf16x8*)&Pb[wave][l15 * 72 + 32 + quad * 8];
#pragma unroll
            for (int t = 0; t < 4; ++t) {
                oacc[0][t] = __builtin_amdgcn_mfma_f32_16x16x32_bf16(ap0, bv0[t], oacc[0][t], 0, 0, 0);
                oacc[0][t] = __builtin_amdgcn_mfma_f32_16x16x32_bf16(ap1, bv1[t], oacc[0][t], 0, 0, 0);
            }
        }
        if (act1) {
            const bf16x8 ap0 = *(const bf16x8*)&Pb[wave][(16 + l15) * 72 + quad * 8];
            const bf16x8 ap1 = *(const bf16x8*)&Pb[wave][(16 + l15) * 72 + 32 + quad * 8];
#pragma unroll
            for (int t = 0; t < 4; ++t) {
                oacc[1][t] = __builtin_amdgcn_mfma_f32_16x16x32_bf16(ap0, bv0[t], oacc[1][t], 0, 0, 0);
                oacc[1][t] = __builtin_amdgcn_mfma_f32_16x16x32_bf16(ap1, bv1[t], oacc[1][t], 0, 0, 0);
            }
        }

        __syncthreads();    // staged buf^1 landed; all waves done reading buf
        buf ^= 1;
    }

    // ---- fused epilogue: 1/l normalize + direct AO bf16 write ----
    const int b = bh >> 4, h = bh & 15;
#pragma unroll
    for (int f = 0; f < 2; ++f) {
        float inv[4];
#pragma unroll
        for (int r = 0; r < 4; ++r) {
            float s = lsum[f][r];
            s += __shfl_xor(s, 1);
            s += __shfl_xor(s, 2);
            s += __shfl_xor(s, 4);
            s += __shfl_xor(s, 8);
            inv[r] = 1.0f / s;
        }
#pragma unroll
        for (int t = 0; t < 4; ++t)
#pragma unroll
            for (int r = 0; r < 4; ++r) {
                const int qa = q0 + 16 * f + quad * 4 + r;
                AO[(size_t)(b * SEQ + qa) * DMODEL + h * 64 + t * 16 + l15] =
                    (bf16_t)(oacc[f][t][r] * inv[r]);
            }
    }
}

extern "C" void kernel_launch(void* const* d_in, const int* in_sizes, int n_in,
                              void* d_out, int out_size, void* d_ws, size_t ws_size,
                              hipStream_t stream) {
    (void)in_sizes; (void)n_in; (void)out_size; (void)ws_size;
    const float* x    = (const float*)d_in[0];
    const int*   pos  = (const int*)d_in[1];
    const float* qkvw = (const float*)d_in[2];
    const float* ow   = (const float*)d_in[3];
    float* out = (float*)d_out;

    const size_t HEAD_ELEMS = (size_t)BATCH * NHEADS * SEQ * DK;  // 4,194,304
    bf16_t* Qw  = (bf16_t*)d_ws;              // 8 MiB
    bf16_t* Kw  = Qw + HEAD_ELEMS;            // 8 MiB
    bf16_t* Vt  = Kw + HEAD_ELEMS;            // 8 MiB (transposed+permuted V)
    bf16_t* AO  = Vt + HEAD_ELEMS;            // 8 MiB — aliased with xb (disjoint live ranges)
    bf16_t* xb  = AO;
    bf16_t* wb  = AO + X_N;                   // 6 MiB
    bf16_t* ob  = wb + W_N;                   // 2 MiB (total ~40 MiB)

    // 1) fp32 -> bf16 for x, qkv_proj, o_proj
    convert_kernel<<<dim3(4096), 256, 0, stream>>>(x, qkvw, ow, xb, wb, ob);
    // 2) QKV projection + fused RoPE -> head-major Q/K, transposed-permuted V
    qkv_gemm_kernel<<<dim3(24, 32), 256, 0, stream>>>(xb, wb, pos, Qw, Kw, Vt);
    // 3) classic flash attention, LDS-shared K/V, fused normalize -> AO bf16
    attn_kernel<<<dim3(512), 256, 0, stream>>>(Qw, Kw, Vt, AO);
    // 4) output projection (128x64 tiles, 512 blocks) -> fp32 d_out
    out_gemm_kernel<<<dim3(16, 32), 256, 0, stream>>>(AO, ob, out);
}

// Round 6
// 193.844 us; speedup vs baseline: 1.3595x; 1.0731x over previous
//
#include <hip/hip_runtime.h>
#include <hip/hip_bf16.h>
#include <math.h>

typedef __bf16 bf16_t;
typedef __attribute__((ext_vector_type(2))) __bf16 bf16x2;
typedef __attribute__((ext_vector_type(4))) __bf16 bf16x4;
typedef __attribute__((ext_vector_type(8))) __bf16 bf16x8;
typedef __attribute__((ext_vector_type(4))) float f32x4;

#define BATCH  2
#define SEQ    2048
#define DMODEL 1024
#define NHEADS 16
#define DK     64

typedef const __attribute__((address_space(1))) void* gas_t;
typedef __attribute__((address_space(3))) void* las_t;

#define X_N (BATCH * SEQ * DMODEL)        // 4,194,304
#define W_N (3 * DMODEL * DMODEL)         // 3,145,728
#define O_N (DMODEL * DMODEL)             // 1,048,576

__global__ __launch_bounds__(256) void convert_kernel(
    const float* __restrict__ x, const float* __restrict__ w, const float* __restrict__ o,
    bf16_t* __restrict__ xb, bf16_t* __restrict__ wb, bf16_t* __restrict__ ob)
{
    const int gid = blockIdx.x * 256 + threadIdx.x;   // 1,048,576 threads
    const float* src; bf16_t* dst; int base = gid * 8;
    if (base < X_N)                { src = x; dst = xb; }
    else if (base < X_N + W_N)     { src = w; dst = wb; base -= X_N; }
    else                           { src = o; dst = ob; base -= X_N + W_N; }
    const f32x4 lo = *(const f32x4*)(src + base);
    const f32x4 hi = *(const f32x4*)(src + base + 4);
    bf16x8 r;
    r[0] = (bf16_t)lo[0]; r[1] = (bf16_t)lo[1]; r[2] = (bf16_t)lo[2]; r[3] = (bf16_t)lo[3];
    r[4] = (bf16_t)hi[0]; r[5] = (bf16_t)hi[1]; r[6] = (bf16_t)hi[2]; r[7] = (bf16_t)hi[3];
    *(bf16x8*)(dst + base) = r;
}

// ---------------------------------------------------------------------------
// m97-style 128x128 GEMM body (qkv only).
// ---------------------------------------------------------------------------
__device__ __forceinline__ void gemm128_body(
    const bf16_t* __restrict__ A, const bf16_t* __restrict__ B,
    int rowBase, int colBase, bf16_t* ldsA, bf16_t* ldsB, f32x4 acc[4][4])
{
    const int tid  = threadIdx.x;
    const int lane = tid & 63;
    const int l15  = lane & 15, quad = lane >> 4;
    const int qr   = ((tid >> 6) >> 1) * 64;
    const int qc   = ((tid >> 6) & 1) * 64;

    const int c0 = tid, c1 = tid + 256;
    const int r0 = c0 >> 2, kc0 = (c0 & 3) * 8;
    const int r1 = c1 >> 2, kc1 = (c1 & 3) * 8;
    const bf16_t* ga0 = A + (size_t)(rowBase + r0) * DMODEL + kc0;
    const bf16_t* ga1 = A + (size_t)(rowBase + r1) * DMODEL + kc1;
    const bf16_t* gb0 = B + (size_t)(colBase + r0) * DMODEL + kc0;
    const bf16_t* gb1 = B + (size_t)(colBase + r1) * DMODEL + kc1;

    for (int k0 = 0; k0 < DMODEL; k0 += 32) {
        __syncthreads();
        __builtin_amdgcn_global_load_lds((gas_t)(ga0 + k0), (las_t)(ldsA + c0 * 8), 16, 0, 0);
        __builtin_amdgcn_global_load_lds((gas_t)(ga1 + k0), (las_t)(ldsA + c1 * 8), 16, 0, 0);
        __builtin_amdgcn_global_load_lds((gas_t)(gb0 + k0), (las_t)(ldsB + c0 * 8), 16, 0, 0);
        __builtin_amdgcn_global_load_lds((gas_t)(gb1 + k0), (las_t)(ldsB + c1 * 8), 16, 0, 0);
        __syncthreads();

        bf16x8 af[4], bfr[4];
#pragma unroll
        for (int i = 0; i < 4; ++i)
            af[i] = *(const bf16x8*)&ldsA[(qr + i * 16 + l15) * 32 + quad * 8];
#pragma unroll
        for (int j = 0; j < 4; ++j)
            bfr[j] = *(const bf16x8*)&ldsB[(qc + j * 16 + l15) * 32 + quad * 8];
#pragma unroll
        for (int i = 0; i < 4; ++i)
#pragma unroll
            for (int j = 0; j < 4; ++j)
                acc[i][j] = __builtin_amdgcn_mfma_f32_16x16x32_bf16(af[i], bfr[j], acc[i][j], 0, 0, 0);
    }
}

// ---------------------------------------------------------------------------
// QKV GEMM with fused RoPE. V is written TRANSPOSED per head with the 64-key
// tile permutation pos(k) = ((k&15)<<2)|(k>>4) — the same permutation the
// attention P-store uses, so PV fragment loads become contiguous bf16x8.
// ---------------------------------------------------------------------------
__global__ __launch_bounds__(256) void qkv_gemm_kernel(
    const bf16_t* __restrict__ x, const bf16_t* __restrict__ w,
    const int* __restrict__ pos,
    bf16_t* __restrict__ qo, bf16_t* __restrict__ ko, bf16_t* __restrict__ vt)
{
    __shared__ bf16_t ldsA[128 * 32];
    __shared__ bf16_t ldsB[128 * 32];
    const int rowBase = blockIdx.y * 128;
    const int colBase = blockIdx.x * 128;
    f32x4 acc[4][4] = {};
    gemm128_body(x, w, rowBase, colBase, ldsA, ldsB, acc);

    const int lane = threadIdx.x & 63;
    const int l15 = lane & 15, quad = lane >> 4;
    const int qr = ((threadIdx.x >> 6) >> 1) * 64;
    const int qc = ((threadIdx.x >> 6) & 1) * 64;
#pragma unroll
    for (int j = 0; j < 4; ++j) {
        const int col  = colBase + qc + j * 16 + l15;
        const int part = col >> 10;             // wave-uniform
        const int h    = (col & 1023) >> 6;
        const int d    = col & 63;
        bf16_t* op = (part == 0) ? qo : (part == 1) ? ko : vt;
        if (part < 2) {
            const float invf  = exp2f(-(float)(d >> 1) * 0.4152410118609203f);
            const float psign = (d & 1) ? 1.f : -1.f;
#pragma unroll
            for (int i = 0; i < 4; ++i) {
#pragma unroll
                for (int r = 0; r < 4; ++r) {
                    const int m = rowBase + qr + i * 16 + quad * 4 + r;
                    const int b = m >> 11;
                    const int s = m & (SEQ - 1);
                    const float ang = (float)pos[s] * invf;
                    const float sn_ = __sinf(ang);
                    const float c_  = __cosf(ang);
                    const float v = acc[i][j][r];
                    const float p = __shfl_xor(v, 1);
                    const float res = fmaf(p, psign * sn_, v * c_);
                    op[((size_t)(b * NHEADS + h) * SEQ + s) * DK + d] = (bf16_t)res;
                }
            }
        } else {
            // V^T permuted store: VT[bh][d][(s&~63) | pos(s&63)]
#pragma unroll
            for (int i = 0; i < 4; ++i) {
#pragma unroll
                for (int r = 0; r < 4; ++r) {
                    const int m = rowBase + qr + i * 16 + quad * 4 + r;
                    const int b = m >> 11;
                    const int s = m & (SEQ - 1);
                    const int sp = (s & ~63) | ((s & 15) << 2) | ((s >> 4) & 3);
                    op[(size_t)(b * NHEADS + h) * SEQ * DK + (size_t)d * SEQ + sp]
                        = (bf16_t)acc[i][j][r];
                }
            }
        }
    }
}

// ---------------------------------------------------------------------------
// Output GEMM: 128x64 tiles -> grid 512 blocks (2/CU).
// ---------------------------------------------------------------------------
__global__ __launch_bounds__(256) void out_gemm_kernel(
    const bf16_t* __restrict__ a, const bf16_t* __restrict__ w, float* __restrict__ out)
{
    __shared__ bf16_t ldsA[128 * 32];
    __shared__ bf16_t ldsB[64 * 32];
    const int tid  = threadIdx.x;
    const int lane = tid & 63;
    const int l15  = lane & 15, quad = lane >> 4;
    const int wv   = tid >> 6;
    const int rowBase = blockIdx.y * 128;
    const int colBase = blockIdx.x * 64;

    const int c0 = tid, c1 = tid + 256;
    const bf16_t* ga0 = a + (size_t)(rowBase + (c0 >> 2)) * DMODEL + (c0 & 3) * 8;
    const bf16_t* ga1 = a + (size_t)(rowBase + (c1 >> 2)) * DMODEL + (c1 & 3) * 8;
    const bf16_t* gb0 = w + (size_t)(colBase + (tid >> 2)) * DMODEL + (tid & 3) * 8;

    f32x4 acc[2][4] = {};
    for (int k0 = 0; k0 < DMODEL; k0 += 32) {
        __syncthreads();
        __builtin_amdgcn_global_load_lds((gas_t)(ga0 + k0), (las_t)(ldsA + c0 * 8), 16, 0, 0);
        __builtin_amdgcn_global_load_lds((gas_t)(ga1 + k0), (las_t)(ldsA + c1 * 8), 16, 0, 0);
        __builtin_amdgcn_global_load_lds((gas_t)(gb0 + k0), (las_t)(ldsB + tid * 8), 16, 0, 0);
        __syncthreads();

        bf16x8 af[2], bfr[4];
#pragma unroll
        for (int i = 0; i < 2; ++i)
            af[i] = *(const bf16x8*)&ldsA[(wv * 32 + i * 16 + l15) * 32 + quad * 8];
#pragma unroll
        for (int j = 0; j < 4; ++j)
            bfr[j] = *(const bf16x8*)&ldsB[(j * 16 + l15) * 32 + quad * 8];
#pragma unroll
        for (int i = 0; i < 2; ++i)
#pragma unroll
            for (int j = 0; j < 4; ++j)
                acc[i][j] = __builtin_amdgcn_mfma_f32_16x16x32_bf16(af[i], bfr[j], acc[i][j], 0, 0, 0);
    }
#pragma unroll
    for (int i = 0; i < 2; ++i) {
#pragma unroll
        for (int r = 0; r < 4; ++r) {
            const int m = rowBase + wv * 32 + i * 16 + quad * 4 + r;
#pragma unroll
            for (int j = 0; j < 4; ++j)
                out[(size_t)m * DMODEL + colBase + j * 16 + l15] = acc[i][j][r];
        }
    }
}

// ---------------------------------------------------------------------------
// Flash attention v12: v11 structure, 8 waves x 16 queries (512 threads).
//   Same 128-query blocks, same LDS-shared double-buffered K/V staging, same
//   math (QK pairing, exp(s-8), P roundtrip, PV, fused normalize). Per-wave
//   serial chain per tile HALVES (8 QK MFMA + 16 exp + 8 PV vs 16+32+16) and
//   waves/SIMD doubles (4 co-resident, 2 in the long-block tail vs 1) —
//   attacks the measured 55% stall (R4: occupancy 12%, 1 wave/SIMD tail).
//   Staging: 512 thr x 16 B = exactly one global_load_lds per thread per
//   tensor per tile; chunk-XOR swizzle unchanged.
// ---------------------------------------------------------------------------
__global__ __launch_bounds__(512) void attn_kernel(
    const bf16_t* __restrict__ Q, const bf16_t* __restrict__ K,
    const bf16_t* __restrict__ VT, bf16_t* __restrict__ AO)
{
    __shared__ bf16_t Kb[2][64 * 64];            // 16 KiB
    __shared__ bf16_t Vb[2][64 * 64];            // 16 KiB
    __shared__ bf16_t Pb[8][16 * 72];            // 18 KiB

    const int bh = blockIdx.x & 31;              // XCD = blk%8 = bh%8
    const int j  = blockIdx.x >> 5;              // 0..15
    const int qb = (j < 8) ? j : 23 - j;         // pair (j, j+8) -> (qb, 15-qb)
    const int nt = 2 * qb + 2;                   // causal tile count

    const int tid  = threadIdx.x;
    const int wave = tid >> 6, lane = tid & 63;
    const int l15  = lane & 15, quad = lane >> 4;
    const int q0   = qb * 128 + wave * 16;       // wave's 16 query rows
    const size_t hb = (size_t)bh * SEQ * DK;

    // staging map: one 16B chunk per thread; r = tid>>3, c = tid&7,
    // source col pre-swizzled (c ^ (r&7)); LDS dest linear tid*8.
    const int sr = tid >> 3;
    const int sc = ((tid & 7) ^ (sr & 7)) * 8;
    const int dd = tid * 8;

    // Q fragment (queries q0..q0+15), pre-scaled by 1/8
    bf16x8 aq0, aq1;
    {
        const bf16_t* qrow = Q + hb + (size_t)(q0 + l15) * DK + quad * 8;
        aq0 = *(const bf16x8*)qrow;
        aq1 = *(const bf16x8*)(qrow + 32);
#pragma unroll
        for (int i = 0; i < 8; ++i) {
            aq0[i] = (bf16_t)((float)aq0[i] * 0.125f);
            aq1[i] = (bf16_t)((float)aq1[i] * 0.125f);
        }
    }

    f32x4 oacc[4] = {};
    float lsum[4] = {};

    // ---- prologue: stage tile 0 into buf 0 ----
    __builtin_amdgcn_global_load_lds((gas_t)(K  + hb + (size_t)sr * DK + sc),
                                     (las_t)(&Kb[0][dd]), 16, 0, 0);
    __builtin_amdgcn_global_load_lds((gas_t)(VT + hb + (size_t)sr * SEQ + sc),
                                     (las_t)(&Vb[0][dd]), 16, 0, 0);
    __syncthreads();

    const int swA = (quad ^ (l15 & 7)) * 8;           // read-side XOR, chunks 0-3
    const int swB = ((4 + quad) ^ (l15 & 7)) * 8;     // chunks 4-7

    int buf = 0;
    for (int kb = 0; kb < nt; ++kb) {
        // ---- stage next tile into buf^1 (overlaps this tile's compute) ----
        if (kb + 1 < nt) {
            const bf16_t* kg = K  + hb + (size_t)(kb + 1) * 64 * DK;
            const bf16_t* vg = VT + hb + (kb + 1) * 64;
            __builtin_amdgcn_global_load_lds((gas_t)(kg + (size_t)sr * DK + sc),
                                             (las_t)(&Kb[buf ^ 1][dd]), 16, 0, 0);
            __builtin_amdgcn_global_load_lds((gas_t)(vg + (size_t)sr * SEQ + sc),
                                             (las_t)(&Vb[buf ^ 1][dd]), 16, 0, 0);
        }

        const bool act = (kb * 64 <= q0 + 15);        // wave-uniform
        const bool nm  = (kb * 64 + 63 > q0);

        if (act) {
            // ---- K fragments from shared LDS tile ----
            bf16x8 kf0[4], kf1[4];
#pragma unroll
            for (int c = 0; c < 4; ++c) {
                kf0[c] = *(const bf16x8*)&Kb[buf][(c * 16 + l15) * 64 + swA];
                kf1[c] = *(const bf16x8*)&Kb[buf][(c * 16 + l15) * 64 + swB];
            }
            // ---- QK scores ----
            f32x4 sc4[4];
#pragma unroll
            for (int c = 0; c < 4; ++c) {
                f32x4 z = {};
                z = __builtin_amdgcn_mfma_f32_16x16x32_bf16(aq0, kf0[c], z, 0, 0, 0);
                z = __builtin_amdgcn_mfma_f32_16x16x32_bf16(aq1, kf1[c], z, 0, 0, 0);
                sc4[c] = z;
            }
            // ---- exp + packed (permuted) P store ----
#pragma unroll
            for (int r = 0; r < 4; ++r) {
                bf16x4 pr;
#pragma unroll
                for (int c = 0; c < 4; ++c) {
                    float s = sc4[c][r];
                    if (nm) {
                        const int key = kb * 64 + c * 16 + l15;
                        const int qa  = q0 + quad * 4 + r;
                        s = (key <= qa) ? s : -INFINITY;
                    }
                    const float p = __expf(s - 8.0f);
                    lsum[r] += p;
                    pr[c] = (bf16_t)p;
                }
                *(bf16x4*)&Pb[wave][(quad * 4 + r) * 72 + l15 * 4] = pr;
            }
            asm volatile("s_waitcnt lgkmcnt(0)" ::: "memory");  // wave-private LDS RAW

            const bf16x8 ap0 = *(const bf16x8*)&Pb[wave][l15 * 72 + quad * 8];
            const bf16x8 ap1 = *(const bf16x8*)&Pb[wave][l15 * 72 + 32 + quad * 8];
            // ---- O += P.V (V fragments from shared LDS tile) ----
#pragma unroll
            for (int t = 0; t < 4; ++t) {
                const bf16x8 bv0 = *(const bf16x8*)&Vb[buf][(t * 16 + l15) * 64 + swA];
                const bf16x8 bv1 = *(const bf16x8*)&Vb[buf][(t * 16 + l15) * 64 + swB];
                oacc[t] = __builtin_amdgcn_mfma_f32_16x16x32_bf16(ap0, bv0, oacc[t], 0, 0, 0);
                oacc[t] = __builtin_amdgcn_mfma_f32_16x16x32_bf16(ap1, bv1, oacc[t], 0, 0, 0);
            }
        }

        __syncthreads();    // staged buf^1 landed; all waves done reading buf
        buf ^= 1;
    }

    // ---- fused epilogue: 1/l normalize + direct AO bf16 write ----
    const int b = bh >> 4, h = bh & 15;
    float inv[4];
#pragma unroll
    for (int r = 0; r < 4; ++r) {
        float s = lsum[r];
        s += __shfl_xor(s, 1);
        s += __shfl_xor(s, 2);
        s += __shfl_xor(s, 4);
        s += __shfl_xor(s, 8);
        inv[r] = 1.0f / s;
    }
#pragma unroll
    for (int t = 0; t < 4; ++t)
#pragma unroll
        for (int r = 0; r < 4; ++r) {
            const int qa = q0 + quad * 4 + r;
            AO[(size_t)(b * SEQ + qa) * DMODEL + h * 64 + t * 16 + l15] =
                (bf16_t)(oacc[t][r] * inv[r]);
        }
}

extern "C" void kernel_launch(void* const* d_in, const int* in_sizes, int n_in,
                              void* d_out, int out_size, void* d_ws, size_t ws_size,
                              hipStream_t stream) {
    (void)in_sizes; (void)n_in; (void)out_size; (void)ws_size;
    const float* x    = (const float*)d_in[0];
    const int*   pos  = (const int*)d_in[1];
    const float* qkvw = (const float*)d_in[2];
    const float* ow   = (const float*)d_in[3];
    float* out = (float*)d_out;

    const size_t HEAD_ELEMS = (size_t)BATCH * NHEADS * SEQ * DK;  // 4,194,304
    bf16_t* Qw  = (bf16_t*)d_ws;              // 8 MiB
    bf16_t* Kw  = Qw + HEAD_ELEMS;            // 8 MiB
    bf16_t* Vt  = Kw + HEAD_ELEMS;            // 8 MiB (transposed+permuted V)
    bf16_t* AO  = Vt + HEAD_ELEMS;            // 8 MiB — aliased with xb (disjoint live ranges)
    bf16_t* xb  = AO;
    bf16_t* wb  = AO + X_N;                   // 6 MiB
    bf16_t* ob  = wb + W_N;                   // 2 MiB (total ~40 MiB)

    // 1) fp32 -> bf16 for x, qkv_proj, o_proj
    convert_kernel<<<dim3(4096), 256, 0, stream>>>(x, qkvw, ow, xb, wb, ob);
    // 2) QKV projection + fused RoPE -> head-major Q/K, transposed-permuted V
    qkv_gemm_kernel<<<dim3(24, 32), 256, 0, stream>>>(xb, wb, pos, Qw, Kw, Vt);
    // 3) classic flash attention, 8 waves x 16 queries, fused normalize
    attn_kernel<<<dim3(512), 512, 0, stream>>>(Qw, Kw, Vt, AO);
    // 4) output projection (128x64 tiles, 512 blocks) -> fp32 d_out
    out_gemm_kernel<<<dim3(16, 32), 256, 0, stream>>>(AO, ob, out);
}

// Round 7
// 184.454 us; speedup vs baseline: 1.4287x; 1.0509x over previous
//
#include <hip/hip_runtime.h>
#include <hip/hip_bf16.h>
#include <math.h>

typedef __bf16 bf16_t;
typedef __attribute__((ext_vector_type(2))) __bf16 bf16x2;
typedef __attribute__((ext_vector_type(4))) __bf16 bf16x4;
typedef __attribute__((ext_vector_type(8))) __bf16 bf16x8;
typedef __attribute__((ext_vector_type(4))) float f32x4;
typedef __attribute__((ext_vector_type(2))) float f32x2;

#define BATCH  2
#define SEQ    2048
#define DMODEL 1024
#define NHEADS 16
#define DK     64

typedef const __attribute__((address_space(1))) void* gas_t;
typedef __attribute__((address_space(3))) void* las_t;

#define X_N (BATCH * SEQ * DMODEL)        // 4,194,304
#define W_N (3 * DMODEL * DMODEL)         // 3,145,728
#define O_N (DMODEL * DMODEL)             // 1,048,576
#define TBL_N (SEQ * 32)                  // 65,536 RoPE (cos,sin) entries

// ---------------------------------------------------------------------------
// Convert fp32->bf16 (blocks < 4096) + RoPE cos/sin table gen (blocks >= 4096).
// Table: tbl[s*32+dp] = {__cosf(pos[s]*invf(dp)), __sinf(...)} — numerically
// identical to the previous in-epilogue __sinf/__cosf.
// ---------------------------------------------------------------------------
__global__ __launch_bounds__(256) void convert_kernel(
    const float* __restrict__ x, const float* __restrict__ w, const float* __restrict__ o,
    const int* __restrict__ pos,
    bf16_t* __restrict__ xb, bf16_t* __restrict__ wb, bf16_t* __restrict__ ob,
    f32x2* __restrict__ tbl)
{
    if (blockIdx.x >= 4096) {
        const int e  = (blockIdx.x - 4096) * 256 + threadIdx.x;   // 0..65535
        const int s  = e >> 5;
        const int dp = e & 31;
        const float ang = (float)pos[s] * exp2f(-(float)dp * 0.4152410118609203f);
        tbl[e] = (f32x2){ __cosf(ang), __sinf(ang) };
        return;
    }
    const int gid = blockIdx.x * 256 + threadIdx.x;   // 1,048,576 threads
    const float* src; bf16_t* dst; int base = gid * 8;
    if (base < X_N)                { src = x; dst = xb; }
    else if (base < X_N + W_N)     { src = w; dst = wb; base -= X_N; }
    else                           { src = o; dst = ob; base -= X_N + W_N; }
    const f32x4 lo = *(const f32x4*)(src + base);
    const f32x4 hi = *(const f32x4*)(src + base + 4);
    bf16x8 r;
    r[0] = (bf16_t)lo[0]; r[1] = (bf16_t)lo[1]; r[2] = (bf16_t)lo[2]; r[3] = (bf16_t)lo[3];
    r[4] = (bf16_t)hi[0]; r[5] = (bf16_t)hi[1]; r[6] = (bf16_t)hi[2]; r[7] = (bf16_t)hi[3];
    *(bf16x8*)(dst + base) = r;
}

// ---------------------------------------------------------------------------
// 128x128 GEMM body, BK=64: half the barriers/drains of the BK=32 version,
// 32 MFMA per drain. LDS tiles [128][64] with chunk-XOR swizzle (pre-swizzled
// global source + linear global_load_lds dest + XOR read) -> conflict-free
// ds_read_b128 (old [row][32] layout was ~8-way conflicted, 3.15M counter).
// ---------------------------------------------------------------------------
__device__ __forceinline__ void gemm128_body(
    const bf16_t* __restrict__ A, const bf16_t* __restrict__ B,
    int rowBase, int colBase, bf16_t* ldsA, bf16_t* ldsB, f32x4 acc[4][4])
{
    const int tid  = threadIdx.x;
    const int lane = tid & 63;
    const int l15  = lane & 15, quad = lane >> 4;
    const int l7   = l15 & 7;
    const int qr   = ((tid >> 6) >> 1) * 64;
    const int qc   = ((tid >> 6) & 1) * 64;

    // staging: row sr (+32/pass), source col chunk pre-swizzled by row
    const int sr   = tid >> 3;                        // 0..31
    const int scol = ((tid & 7) ^ (sr & 7)) * 8;
    const bf16_t* ga = A + (size_t)(rowBase + sr) * DMODEL + scol;
    const bf16_t* gb = B + (size_t)(colBase + sr) * DMODEL + scol;
    const int dd = tid * 8;

    for (int k0 = 0; k0 < DMODEL; k0 += 64) {
        __syncthreads();
#pragma unroll
        for (int u = 0; u < 4; ++u) {
            __builtin_amdgcn_global_load_lds((gas_t)(ga + k0 + (size_t)u * 32 * DMODEL),
                                             (las_t)(ldsA + dd + u * 2048), 16, 0, 0);
            __builtin_amdgcn_global_load_lds((gas_t)(gb + k0 + (size_t)u * 32 * DMODEL),
                                             (las_t)(ldsB + dd + u * 2048), 16, 0, 0);
        }
        __syncthreads();

#pragma unroll
        for (int kk = 0; kk < 2; ++kk) {
            const int sw = ((kk * 4 + quad) ^ l7) * 8;
            bf16x8 af[4], bfr[4];
#pragma unroll
            for (int i = 0; i < 4; ++i)
                af[i] = *(const bf16x8*)&ldsA[(qr + i * 16 + l15) * 64 + sw];
#pragma unroll
            for (int j = 0; j < 4; ++j)
                bfr[j] = *(const bf16x8*)&ldsB[(qc + j * 16 + l15) * 64 + sw];
#pragma unroll
            for (int i = 0; i < 4; ++i)
#pragma unroll
                for (int j = 0; j < 4; ++j)
                    acc[i][j] = __builtin_amdgcn_mfma_f32_16x16x32_bf16(af[i], bfr[j], acc[i][j], 0, 0, 0);
        }
    }
}

// ---------------------------------------------------------------------------
// QKV GEMM with fused RoPE (table-driven). V written transposed+permuted.
// ---------------------------------------------------------------------------
__global__ __launch_bounds__(256) void qkv_gemm_kernel(
    const bf16_t* __restrict__ x, const bf16_t* __restrict__ w,
    const f32x2* __restrict__ tbl,
    bf16_t* __restrict__ qo, bf16_t* __restrict__ ko, bf16_t* __restrict__ vt)
{
    __shared__ bf16_t ldsA[128 * 64];
    __shared__ bf16_t ldsB[128 * 64];
    const int rowBase = blockIdx.y * 128;
    const int colBase = blockIdx.x * 128;
    f32x4 acc[4][4] = {};
    gemm128_body(x, w, rowBase, colBase, ldsA, ldsB, acc);

    const int lane = threadIdx.x & 63;
    const int l15 = lane & 15, quad = lane >> 4;
    const int qr = ((threadIdx.x >> 6) >> 1) * 64;
    const int qc = ((threadIdx.x >> 6) & 1) * 64;
#pragma unroll
    for (int j = 0; j < 4; ++j) {
        const int col  = colBase + qc + j * 16 + l15;
        const int part = col >> 10;             // wave-uniform
        const int h    = (col & 1023) >> 6;
        const int d    = col & 63;
        bf16_t* op = (part == 0) ? qo : (part == 1) ? ko : vt;
        if (part < 2) {
            const float psign = (d & 1) ? 1.f : -1.f;
            const f32x2* trow = tbl + (d >> 1);
#pragma unroll
            for (int i = 0; i < 4; ++i) {
#pragma unroll
                for (int r = 0; r < 4; ++r) {
                    const int m = rowBase + qr + i * 16 + quad * 4 + r;
                    const int b = m >> 11;
                    const int s = m & (SEQ - 1);
                    const f32x2 cs = trow[s * 32];
                    const float v = acc[i][j][r];
                    const float p = __shfl_xor(v, 1);
                    const float res = fmaf(p, psign * cs[1], v * cs[0]);
                    op[((size_t)(b * NHEADS + h) * SEQ + s) * DK + d] = (bf16_t)res;
                }
            }
        } else {
            // V^T permuted store: VT[bh][d][(s&~63) | pos(s&63)]
#pragma unroll
            for (int i = 0; i < 4; ++i) {
#pragma unroll
                for (int r = 0; r < 4; ++r) {
                    const int m = rowBase + qr + i * 16 + quad * 4 + r;
                    const int b = m >> 11;
                    const int s = m & (SEQ - 1);
                    const int sp = (s & ~63) | ((s & 15) << 2) | ((s >> 4) & 3);
                    op[(size_t)(b * NHEADS + h) * SEQ * DK + (size_t)d * SEQ + sp]
                        = (bf16_t)acc[i][j][r];
                }
            }
        }
    }
}

// ---------------------------------------------------------------------------
// Output GEMM: 128x64 tiles, BK=64 + chunk-XOR swizzle (same scheme).
// ---------------------------------------------------------------------------
__global__ __launch_bounds__(256) void out_gemm_kernel(
    const bf16_t* __restrict__ a, const bf16_t* __restrict__ w, float* __restrict__ out)
{
    __shared__ bf16_t ldsA[128 * 64];
    __shared__ bf16_t ldsB[64 * 64];
    const int tid  = threadIdx.x;
    const int lane = tid & 63;
    const int l15  = lane & 15, quad = lane >> 4;
    const int l7   = l15 & 7;
    const int wv   = tid >> 6;
    const int rowBase = blockIdx.y * 128;
    const int colBase = blockIdx.x * 64;

    const int sr   = tid >> 3;
    const int scol = ((tid & 7) ^ (sr & 7)) * 8;
    const bf16_t* ga = a + (size_t)(rowBase + sr) * DMODEL + scol;
    const bf16_t* gb = w + (size_t)(colBase + sr) * DMODEL + scol;
    const int dd = tid * 8;

    f32x4 acc[2][4] = {};
    for (int k0 = 0; k0 < DMODEL; k0 += 64) {
        __syncthreads();
#pragma unroll
        for (int u = 0; u < 4; ++u)
            __builtin_amdgcn_global_load_lds((gas_t)(ga + k0 + (size_t)u * 32 * DMODEL),
                                             (las_t)(ldsA + dd + u * 2048), 16, 0, 0);
#pragma unroll
        for (int u = 0; u < 2; ++u)
            __builtin_amdgcn_global_load_lds((gas_t)(gb + k0 + (size_t)u * 32 * DMODEL),
                                             (las_t)(ldsB + dd + u * 2048), 16, 0, 0);
        __syncthreads();

#pragma unroll
        for (int kk = 0; kk < 2; ++kk) {
            const int sw = ((kk * 4 + quad) ^ l7) * 8;
            bf16x8 af[2], bfr[4];
#pragma unroll
            for (int i = 0; i < 2; ++i)
                af[i] = *(const bf16x8*)&ldsA[(wv * 32 + i * 16 + l15) * 64 + sw];
#pragma unroll
            for (int j = 0; j < 4; ++j)
                bfr[j] = *(const bf16x8*)&ldsB[(j * 16 + l15) * 64 + sw];
#pragma unroll
            for (int i = 0; i < 2; ++i)
#pragma unroll
                for (int j = 0; j < 4; ++j)
                    acc[i][j] = __builtin_amdgcn_mfma_f32_16x16x32_bf16(af[i], bfr[j], acc[i][j], 0, 0, 0);
        }
    }
#pragma unroll
    for (int i = 0; i < 2; ++i) {
#pragma unroll
        for (int r = 0; r < 4; ++r) {
            const int m = rowBase + wv * 32 + i * 16 + quad * 4 + r;
#pragma unroll
            for (int j = 0; j < 4; ++j)
                out[(size_t)m * DMODEL + colBase + j * 16 + l15] = acc[i][j][r];
        }
    }
}

// ---------------------------------------------------------------------------
// Flash attention v12 (unchanged from R5): 128-query blocks, 8 waves x 16
// queries, LDS-shared double-buffered K/V, fused normalize, no atomics.
// ---------------------------------------------------------------------------
__global__ __launch_bounds__(512) void attn_kernel(
    const bf16_t* __restrict__ Q, const bf16_t* __restrict__ K,
    const bf16_t* __restrict__ VT, bf16_t* __restrict__ AO)
{
    __shared__ bf16_t Kb[2][64 * 64];            // 16 KiB
    __shared__ bf16_t Vb[2][64 * 64];            // 16 KiB
    __shared__ bf16_t Pb[8][16 * 72];            // 18 KiB

    const int bh = blockIdx.x & 31;              // XCD = blk%8 = bh%8
    const int j  = blockIdx.x >> 5;              // 0..15
    const int qb = (j < 8) ? j : 23 - j;         // pair (j, j+8) -> (qb, 15-qb)
    const int nt = 2 * qb + 2;                   // causal tile count

    const int tid  = threadIdx.x;
    const int wave = tid >> 6, lane = tid & 63;
    const int l15  = lane & 15, quad = lane >> 4;
    const int q0   = qb * 128 + wave * 16;       // wave's 16 query rows
    const size_t hb = (size_t)bh * SEQ * DK;

    const int sr = tid >> 3;
    const int sc = ((tid & 7) ^ (sr & 7)) * 8;
    const int dd = tid * 8;

    // Q fragment (queries q0..q0+15), pre-scaled by 1/8
    bf16x8 aq0, aq1;
    {
        const bf16_t* qrow = Q + hb + (size_t)(q0 + l15) * DK + quad * 8;
        aq0 = *(const bf16x8*)qrow;
        aq1 = *(const bf16x8*)(qrow + 32);
#pragma unroll
        for (int i = 0; i < 8; ++i) {
            aq0[i] = (bf16_t)((float)aq0[i] * 0.125f);
            aq1[i] = (bf16_t)((float)aq1[i] * 0.125f);
        }
    }

    f32x4 oacc[4] = {};
    float lsum[4] = {};

    // ---- prologue: stage tile 0 into buf 0 ----
    __builtin_amdgcn_global_load_lds((gas_t)(K  + hb + (size_t)sr * DK + sc),
                                     (las_t)(&Kb[0][dd]), 16, 0, 0);
    __builtin_amdgcn_global_load_lds((gas_t)(VT + hb + (size_t)sr * SEQ + sc),
                                     (las_t)(&Vb[0][dd]), 16, 0, 0);
    __syncthreads();

    const int swA = (quad ^ (l15 & 7)) * 8;           // read-side XOR, chunks 0-3
    const int swB = ((4 + quad) ^ (l15 & 7)) * 8;     // chunks 4-7

    int buf = 0;
    for (int kb = 0; kb < nt; ++kb) {
        // ---- stage next tile into buf^1 (overlaps this tile's compute) ----
        if (kb + 1 < nt) {
            const bf16_t* kg = K  + hb + (size_t)(kb + 1) * 64 * DK;
            const bf16_t* vg = VT + hb + (kb + 1) * 64;
            __builtin_amdgcn_global_load_lds((gas_t)(kg + (size_t)sr * DK + sc),
                                             (las_t)(&Kb[buf ^ 1][dd]), 16, 0, 0);
            __builtin_amdgcn_global_load_lds((gas_t)(vg + (size_t)sr * SEQ + sc),
                                             (las_t)(&Vb[buf ^ 1][dd]), 16, 0, 0);
        }

        const bool act = (kb * 64 <= q0 + 15);        // wave-uniform
        const bool nm  = (kb * 64 + 63 > q0);

        if (act) {
            bf16x8 kf0[4], kf1[4];
#pragma unroll
            for (int c = 0; c < 4; ++c) {
                kf0[c] = *(const bf16x8*)&Kb[buf][(c * 16 + l15) * 64 + swA];
                kf1[c] = *(const bf16x8*)&Kb[buf][(c * 16 + l15) * 64 + swB];
            }
            f32x4 sc4[4];
#pragma unroll
            for (int c = 0; c < 4; ++c) {
                f32x4 z = {};
                z = __builtin_amdgcn_mfma_f32_16x16x32_bf16(aq0, kf0[c], z, 0, 0, 0);
                z = __builtin_amdgcn_mfma_f32_16x16x32_bf16(aq1, kf1[c], z, 0, 0, 0);
                sc4[c] = z;
            }
#pragma unroll
            for (int r = 0; r < 4; ++r) {
                bf16x4 pr;
#pragma unroll
                for (int c = 0; c < 4; ++c) {
                    float s = sc4[c][r];
                    if (nm) {
                        const int key = kb * 64 + c * 16 + l15;
                        const int qa  = q0 + quad * 4 + r;
                        s = (key <= qa) ? s : -INFINITY;
                    }
                    const float p = __expf(s - 8.0f);
                    lsum[r] += p;
                    pr[c] = (bf16_t)p;
                }
                *(bf16x4*)&Pb[wave][(quad * 4 + r) * 72 + l15 * 4] = pr;
            }
            asm volatile("s_waitcnt lgkmcnt(0)" ::: "memory");  // wave-private LDS RAW

            const bf16x8 ap0 = *(const bf16x8*)&Pb[wave][l15 * 72 + quad * 8];
            const bf16x8 ap1 = *(const bf16x8*)&Pb[wave][l15 * 72 + 32 + quad * 8];
#pragma unroll
            for (int t = 0; t < 4; ++t) {
                const bf16x8 bv0 = *(const bf16x8*)&Vb[buf][(t * 16 + l15) * 64 + swA];
                const bf16x8 bv1 = *(const bf16x8*)&Vb[buf][(t * 16 + l15) * 64 + swB];
                oacc[t] = __builtin_amdgcn_mfma_f32_16x16x32_bf16(ap0, bv0, oacc[t], 0, 0, 0);
                oacc[t] = __builtin_amdgcn_mfma_f32_16x16x32_bf16(ap1, bv1, oacc[t], 0, 0, 0);
            }
        }

        __syncthreads();    // staged buf^1 landed; all waves done reading buf
        buf ^= 1;
    }

    // ---- fused epilogue: 1/l normalize + direct AO bf16 write ----
    const int b = bh >> 4, h = bh & 15;
    float inv[4];
#pragma unroll
    for (int r = 0; r < 4; ++r) {
        float s = lsum[r];
        s += __shfl_xor(s, 1);
        s += __shfl_xor(s, 2);
        s += __shfl_xor(s, 4);
        s += __shfl_xor(s, 8);
        inv[r] = 1.0f / s;
    }
#pragma unroll
    for (int t = 0; t < 4; ++t)
#pragma unroll
        for (int r = 0; r < 4; ++r) {
            const int qa = q0 + quad * 4 + r;
            AO[(size_t)(b * SEQ + qa) * DMODEL + h * 64 + t * 16 + l15] =
                (bf16_t)(oacc[t][r] * inv[r]);
        }
}

extern "C" void kernel_launch(void* const* d_in, const int* in_sizes, int n_in,
                              void* d_out, int out_size, void* d_ws, size_t ws_size,
                              hipStream_t stream) {
    (void)in_sizes; (void)n_in; (void)out_size; (void)ws_size;
    const float* x    = (const float*)d_in[0];
    const int*   pos  = (const int*)d_in[1];
    const float* qkvw = (const float*)d_in[2];
    const float* ow   = (const float*)d_in[3];
    float* out = (float*)d_out;

    const size_t HEAD_ELEMS = (size_t)BATCH * NHEADS * SEQ * DK;  // 4,194,304
    bf16_t* Qw  = (bf16_t*)d_ws;              // 8 MiB
    bf16_t* Kw  = Qw + HEAD_ELEMS;            // 8 MiB
    bf16_t* Vt  = Kw + HEAD_ELEMS;            // 8 MiB (transposed+permuted V)
    bf16_t* AO  = Vt + HEAD_ELEMS;            // 8 MiB — aliased with xb (disjoint live ranges)
    bf16_t* xb  = AO;
    bf16_t* wb  = AO + X_N;                   // 6 MiB
    bf16_t* ob  = wb + W_N;                   // 2 MiB
    f32x2*  tbl = (f32x2*)(ob + O_N);         // 512 KiB RoPE table (~40.5 MiB total)

    // 1) fp32 -> bf16 + RoPE cos/sin table
    convert_kernel<<<dim3(4096 + 256), 256, 0, stream>>>(x, qkvw, ow, pos, xb, wb, ob, tbl);
    // 2) QKV projection + table-driven RoPE -> head-major Q/K, transposed V
    qkv_gemm_kernel<<<dim3(24, 32), 256, 0, stream>>>(xb, wb, tbl, Qw, Kw, Vt);
    // 3) classic flash attention, 8 waves x 16 queries, fused normalize
    attn_kernel<<<dim3(512), 512, 0, stream>>>(Qw, Kw, Vt, AO);
    // 4) output projection (128x64 tiles, BK=64) -> fp32 d_out
    out_gemm_kernel<<<dim3(16, 32), 256, 0, stream>>>(AO, ob, out);
}

// Round 8
// 184.184 us; speedup vs baseline: 1.4308x; 1.0015x over previous
//
#include <hip/hip_runtime.h>
#include <hip/hip_bf16.h>
#include <math.h>

typedef __bf16 bf16_t;
typedef __attribute__((ext_vector_type(2))) __bf16 bf16x2;
typedef __attribute__((ext_vector_type(4))) __bf16 bf16x4;
typedef __attribute__((ext_vector_type(8))) __bf16 bf16x8;
typedef __attribute__((ext_vector_type(4))) float f32x4;
typedef __attribute__((ext_vector_type(2))) float f32x2;

#define BATCH  2
#define SEQ    2048
#define DMODEL 1024
#define NHEADS 16
#define DK     64

typedef const __attribute__((address_space(1))) void* gas_t;
typedef __attribute__((address_space(3))) void* las_t;

#define X_N (BATCH * SEQ * DMODEL)        // 4,194,304
#define W_N (3 * DMODEL * DMODEL)         // 3,145,728
#define O_N (DMODEL * DMODEL)             // 1,048,576

// ---------------------------------------------------------------------------
// Convert fp32->bf16 (blocks < 4096) + RoPE cos/sin table gen (blocks >= 4096).
// ---------------------------------------------------------------------------
__global__ __launch_bounds__(256) void convert_kernel(
    const float* __restrict__ x, const float* __restrict__ w, const float* __restrict__ o,
    const int* __restrict__ pos,
    bf16_t* __restrict__ xb, bf16_t* __restrict__ wb, bf16_t* __restrict__ ob,
    f32x2* __restrict__ tbl)
{
    if (blockIdx.x >= 4096) {
        const int e  = (blockIdx.x - 4096) * 256 + threadIdx.x;   // 0..65535
        const int s  = e >> 5;
        const int dp = e & 31;
        const float ang = (float)pos[s] * exp2f(-(float)dp * 0.4152410118609203f);
        tbl[e] = (f32x2){ __cosf(ang), __sinf(ang) };
        return;
    }
    const int gid = blockIdx.x * 256 + threadIdx.x;   // 1,048,576 threads
    const float* src; bf16_t* dst; int base = gid * 8;
    if (base < X_N)                { src = x; dst = xb; }
    else if (base < X_N + W_N)     { src = w; dst = wb; base -= X_N; }
    else                           { src = o; dst = ob; base -= X_N + W_N; }
    const f32x4 lo = *(const f32x4*)(src + base);
    const f32x4 hi = *(const f32x4*)(src + base + 4);
    bf16x8 r;
    r[0] = (bf16_t)lo[0]; r[1] = (bf16_t)lo[1]; r[2] = (bf16_t)lo[2]; r[3] = (bf16_t)lo[3];
    r[4] = (bf16_t)hi[0]; r[5] = (bf16_t)hi[1]; r[6] = (bf16_t)hi[2]; r[7] = (bf16_t)hi[3];
    *(bf16x8*)(dst + base) = r;
}

// ---------------------------------------------------------------------------
// 128x128 GEMM body, BK=64, DOUBLE-BUFFERED (attn-proven schedule): issue
// next K-tile's global_load_lds at iteration TOP, compute current buffer,
// ONE barrier at bottom. The barrier's implicit vmcnt(0) drain then costs
// ~nothing (prefetch had a full tile of compute to land) — unlike the R6
// 2-phase loop which issued loads between barriers and ate full L2 latency
// every step. Same chunk-XOR swizzled layout (measured 0 bank conflicts).
// ---------------------------------------------------------------------------
__device__ __forceinline__ void gemm128_body(
    const bf16_t* __restrict__ A, const bf16_t* __restrict__ B,
    int rowBase, int colBase, bf16_t* ldsA, bf16_t* ldsB, f32x4 acc[4][4])
{
    const int tid  = threadIdx.x;
    const int lane = tid & 63;
    const int l15  = lane & 15, quad = lane >> 4;
    const int l7   = l15 & 7;
    const int qr   = ((tid >> 6) >> 1) * 64;
    const int qc   = ((tid >> 6) & 1) * 64;

    // staging: row sr (+32/u-pass), source col chunk pre-swizzled by row
    const int sr   = tid >> 3;                        // 0..31
    const int scol = ((tid & 7) ^ (sr & 7)) * 8;
    const bf16_t* ga = A + (size_t)(rowBase + sr) * DMODEL + scol;
    const bf16_t* gb = B + (size_t)(colBase + sr) * DMODEL + scol;
    const int dd = tid * 8;

    // ---- prologue: stage K-tile 0 into buf 0 ----
#pragma unroll
    for (int u = 0; u < 4; ++u) {
        __builtin_amdgcn_global_load_lds((gas_t)(ga + (size_t)u * 32 * DMODEL),
                                         (las_t)(ldsA + dd + u * 2048), 16, 0, 0);
        __builtin_amdgcn_global_load_lds((gas_t)(gb + (size_t)u * 32 * DMODEL),
                                         (las_t)(ldsB + dd + u * 2048), 16, 0, 0);
    }
    __syncthreads();

    int buf = 0;
    for (int k0 = 0; k0 < DMODEL; k0 += 64) {
        // ---- stage next K-tile into buf^1 (overlaps this tile's compute) ----
        if (k0 + 64 < DMODEL) {
            const int off = (buf ^ 1) * 8192;
#pragma unroll
            for (int u = 0; u < 4; ++u) {
                __builtin_amdgcn_global_load_lds((gas_t)(ga + k0 + 64 + (size_t)u * 32 * DMODEL),
                                                 (las_t)(ldsA + off + dd + u * 2048), 16, 0, 0);
                __builtin_amdgcn_global_load_lds((gas_t)(gb + k0 + 64 + (size_t)u * 32 * DMODEL),
                                                 (las_t)(ldsB + off + dd + u * 2048), 16, 0, 0);
            }
        }
        const bf16_t* La = ldsA + buf * 8192;
        const bf16_t* Lb = ldsB + buf * 8192;
#pragma unroll
        for (int kk = 0; kk < 2; ++kk) {
            const int sw = ((kk * 4 + quad) ^ l7) * 8;
            bf16x8 af[4], bfr[4];
#pragma unroll
            for (int i = 0; i < 4; ++i)
                af[i] = *(const bf16x8*)&La[(qr + i * 16 + l15) * 64 + sw];
#pragma unroll
            for (int j = 0; j < 4; ++j)
                bfr[j] = *(const bf16x8*)&Lb[(qc + j * 16 + l15) * 64 + sw];
#pragma unroll
            for (int i = 0; i < 4; ++i)
#pragma unroll
                for (int j = 0; j < 4; ++j)
                    acc[i][j] = __builtin_amdgcn_mfma_f32_16x16x32_bf16(af[i], bfr[j], acc[i][j], 0, 0, 0);
        }
        __syncthreads();   // staged buf^1 landed; all waves done reading buf
        buf ^= 1;
    }
}

// ---------------------------------------------------------------------------
// QKV GEMM with fused RoPE (table-driven). V written transposed+permuted.
// ---------------------------------------------------------------------------
__global__ __launch_bounds__(256) void qkv_gemm_kernel(
    const bf16_t* __restrict__ x, const bf16_t* __restrict__ w,
    const f32x2* __restrict__ tbl,
    bf16_t* __restrict__ qo, bf16_t* __restrict__ ko, bf16_t* __restrict__ vt)
{
    __shared__ bf16_t ldsA[2 * 128 * 64];        // 32 KiB
    __shared__ bf16_t ldsB[2 * 128 * 64];        // 32 KiB
    const int rowBase = blockIdx.y * 128;
    const int colBase = blockIdx.x * 128;
    f32x4 acc[4][4] = {};
    gemm128_body(x, w, rowBase, colBase, ldsA, ldsB, acc);

    const int lane = threadIdx.x & 63;
    const int l15 = lane & 15, quad = lane >> 4;
    const int qr = ((threadIdx.x >> 6) >> 1) * 64;
    const int qc = ((threadIdx.x >> 6) & 1) * 64;
#pragma unroll
    for (int j = 0; j < 4; ++j) {
        const int col  = colBase + qc + j * 16 + l15;
        const int part = col >> 10;             // wave-uniform
        const int h    = (col & 1023) >> 6;
        const int d    = col & 63;
        bf16_t* op = (part == 0) ? qo : (part == 1) ? ko : vt;
        if (part < 2) {
            const float psign = (d & 1) ? 1.f : -1.f;
            const f32x2* trow = tbl + (d >> 1);
#pragma unroll
            for (int i = 0; i < 4; ++i) {
#pragma unroll
                for (int r = 0; r < 4; ++r) {
                    const int m = rowBase + qr + i * 16 + quad * 4 + r;
                    const int b = m >> 11;
                    const int s = m & (SEQ - 1);
                    const f32x2 cs = trow[s * 32];
                    const float v = acc[i][j][r];
                    const float p = __shfl_xor(v, 1);
                    const float res = fmaf(p, psign * cs[1], v * cs[0]);
                    op[((size_t)(b * NHEADS + h) * SEQ + s) * DK + d] = (bf16_t)res;
                }
            }
        } else {
            // V^T permuted store: VT[bh][d][(s&~63) | pos(s&63)]
#pragma unroll
            for (int i = 0; i < 4; ++i) {
#pragma unroll
                for (int r = 0; r < 4; ++r) {
                    const int m = rowBase + qr + i * 16 + quad * 4 + r;
                    const int b = m >> 11;
                    const int s = m & (SEQ - 1);
                    const int sp = (s & ~63) | ((s & 15) << 2) | ((s >> 4) & 3);
                    op[(size_t)(b * NHEADS + h) * SEQ * DK + (size_t)d * SEQ + sp]
                        = (bf16_t)acc[i][j][r];
                }
            }
        }
    }
}

// ---------------------------------------------------------------------------
// Output GEMM: 128x64 tiles, BK=64, same double-buffered schedule.
// ---------------------------------------------------------------------------
__global__ __launch_bounds__(256) void out_gemm_kernel(
    const bf16_t* __restrict__ a, const bf16_t* __restrict__ w, float* __restrict__ out)
{
    __shared__ bf16_t ldsA[2 * 128 * 64];        // 32 KiB
    __shared__ bf16_t ldsB[2 * 64 * 64];         // 16 KiB
    const int tid  = threadIdx.x;
    const int lane = tid & 63;
    const int l15  = lane & 15, quad = lane >> 4;
    const int l7   = l15 & 7;
    const int wv   = tid >> 6;
    const int rowBase = blockIdx.y * 128;
    const int colBase = blockIdx.x * 64;

    const int sr   = tid >> 3;
    const int scol = ((tid & 7) ^ (sr & 7)) * 8;
    const bf16_t* ga = a + (size_t)(rowBase + sr) * DMODEL + scol;
    const bf16_t* gb = w + (size_t)(colBase + sr) * DMODEL + scol;
    const int dd = tid * 8;

    // ---- prologue: stage K-tile 0 into buf 0 ----
#pragma unroll
    for (int u = 0; u < 4; ++u)
        __builtin_amdgcn_global_load_lds((gas_t)(ga + (size_t)u * 32 * DMODEL),
                                         (las_t)(ldsA + dd + u * 2048), 16, 0, 0);
#pragma unroll
    for (int u = 0; u < 2; ++u)
        __builtin_amdgcn_global_load_lds((gas_t)(gb + (size_t)u * 32 * DMODEL),
                                         (las_t)(ldsB + dd + u * 2048), 16, 0, 0);
    __syncthreads();

    f32x4 acc[2][4] = {};
    int buf = 0;
    for (int k0 = 0; k0 < DMODEL; k0 += 64) {
        if (k0 + 64 < DMODEL) {
            const int offA = (buf ^ 1) * 8192, offB = (buf ^ 1) * 4096;
#pragma unroll
            for (int u = 0; u < 4; ++u)
                __builtin_amdgcn_global_load_lds((gas_t)(ga + k0 + 64 + (size_t)u * 32 * DMODEL),
                                                 (las_t)(ldsA + offA + dd + u * 2048), 16, 0, 0);
#pragma unroll
            for (int u = 0; u < 2; ++u)
                __builtin_amdgcn_global_load_lds((gas_t)(gb + k0 + 64 + (size_t)u * 32 * DMODEL),
                                                 (las_t)(ldsB + offB + dd + u * 2048), 16, 0, 0);
        }
        const bf16_t* La = ldsA + buf * 8192;
        const bf16_t* Lb = ldsB + buf * 4096;
#pragma unroll
        for (int kk = 0; kk < 2; ++kk) {
            const int sw = ((kk * 4 + quad) ^ l7) * 8;
            bf16x8 af[2], bfr[4];
#pragma unroll
            for (int i = 0; i < 2; ++i)
                af[i] = *(const bf16x8*)&La[(wv * 32 + i * 16 + l15) * 64 + sw];
#pragma unroll
            for (int j = 0; j < 4; ++j)
                bfr[j] = *(const bf16x8*)&Lb[(j * 16 + l15) * 64 + sw];
#pragma unroll
            for (int i = 0; i < 2; ++i)
#pragma unroll
                for (int j = 0; j < 4; ++j)
                    acc[i][j] = __builtin_amdgcn_mfma_f32_16x16x32_bf16(af[i], bfr[j], acc[i][j], 0, 0, 0);
        }
        __syncthreads();
        buf ^= 1;
    }
#pragma unroll
    for (int i = 0; i < 2; ++i) {
#pragma unroll
        for (int r = 0; r < 4; ++r) {
            const int m = rowBase + wv * 32 + i * 16 + quad * 4 + r;
#pragma unroll
            for (int j = 0; j < 4; ++j)
                out[(size_t)m * DMODEL + colBase + j * 16 + l15] = acc[i][j][r];
        }
    }
}

// ---------------------------------------------------------------------------
// Flash attention v12 (unchanged): 128-query blocks, 8 waves x 16 queries,
// LDS-shared double-buffered K/V, fused normalize, no atomics.
// ---------------------------------------------------------------------------
__global__ __launch_bounds__(512) void attn_kernel(
    const bf16_t* __restrict__ Q, const bf16_t* __restrict__ K,
    const bf16_t* __restrict__ VT, bf16_t* __restrict__ AO)
{
    __shared__ bf16_t Kb[2][64 * 64];            // 16 KiB
    __shared__ bf16_t Vb[2][64 * 64];            // 16 KiB
    __shared__ bf16_t Pb[8][16 * 72];            // 18 KiB

    const int bh = blockIdx.x & 31;              // XCD = blk%8 = bh%8
    const int j  = blockIdx.x >> 5;              // 0..15
    const int qb = (j < 8) ? j : 23 - j;         // pair (j, j+8) -> (qb, 15-qb)
    const int nt = 2 * qb + 2;                   // causal tile count

    const int tid  = threadIdx.x;
    const int wave = tid >> 6, lane = tid & 63;
    const int l15  = lane & 15, quad = lane >> 4;
    const int q0   = qb * 128 + wave * 16;       // wave's 16 query rows
    const size_t hb = (size_t)bh * SEQ * DK;

    const int sr = tid >> 3;
    const int sc = ((tid & 7) ^ (sr & 7)) * 8;
    const int dd = tid * 8;

    // Q fragment (queries q0..q0+15), pre-scaled by 1/8
    bf16x8 aq0, aq1;
    {
        const bf16_t* qrow = Q + hb + (size_t)(q0 + l15) * DK + quad * 8;
        aq0 = *(const bf16x8*)qrow;
        aq1 = *(const bf16x8*)(qrow + 32);
#pragma unroll
        for (int i = 0; i < 8; ++i) {
            aq0[i] = (bf16_t)((float)aq0[i] * 0.125f);
            aq1[i] = (bf16_t)((float)aq1[i] * 0.125f);
        }
    }

    f32x4 oacc[4] = {};
    float lsum[4] = {};

    // ---- prologue: stage tile 0 into buf 0 ----
    __builtin_amdgcn_global_load_lds((gas_t)(K  + hb + (size_t)sr * DK + sc),
                                     (las_t)(&Kb[0][dd]), 16, 0, 0);
    __builtin_amdgcn_global_load_lds((gas_t)(VT + hb + (size_t)sr * SEQ + sc),
                                     (las_t)(&Vb[0][dd]), 16, 0, 0);
    __syncthreads();

    const int swA = (quad ^ (l15 & 7)) * 8;           // read-side XOR, chunks 0-3
    const int swB = ((4 + quad) ^ (l15 & 7)) * 8;     // chunks 4-7

    int buf = 0;
    for (int kb = 0; kb < nt; ++kb) {
        // ---- stage next tile into buf^1 (overlaps this tile's compute) ----
        if (kb + 1 < nt) {
            const bf16_t* kg = K  + hb + (size_t)(kb + 1) * 64 * DK;
            const bf16_t* vg = VT + hb + (kb + 1) * 64;
            __builtin_amdgcn_global_load_lds((gas_t)(kg + (size_t)sr * DK + sc),
                                             (las_t)(&Kb[buf ^ 1][dd]), 16, 0, 0);
            __builtin_amdgcn_global_load_lds((gas_t)(vg + (size_t)sr * SEQ + sc),
                                             (las_t)(&Vb[buf ^ 1][dd]), 16, 0, 0);
        }

        const bool act = (kb * 64 <= q0 + 15);        // wave-uniform
        const bool nm  = (kb * 64 + 63 > q0);

        if (act) {
            bf16x8 kf0[4], kf1[4];
#pragma unroll
            for (int c = 0; c < 4; ++c) {
                kf0[c] = *(const bf16x8*)&Kb[buf][(c * 16 + l15) * 64 + swA];
                kf1[c] = *(const bf16x8*)&Kb[buf][(c * 16 + l15) * 64 + swB];
            }
            f32x4 sc4[4];
#pragma unroll
            for (int c = 0; c < 4; ++c) {
                f32x4 z = {};
                z = __builtin_amdgcn_mfma_f32_16x16x32_bf16(aq0, kf0[c], z, 0, 0, 0);
                z = __builtin_amdgcn_mfma_f32_16x16x32_bf16(aq1, kf1[c], z, 0, 0, 0);
                sc4[c] = z;
            }
#pragma unroll
            for (int r = 0; r < 4; ++r) {
                bf16x4 pr;
#pragma unroll
                for (int c = 0; c < 4; ++c) {
                    float s = sc4[c][r];
                    if (nm) {
                        const int key = kb * 64 + c * 16 + l15;
                        const int qa  = q0 + quad * 4 + r;
                        s = (key <= qa) ? s : -INFINITY;
                    }
                    const float p = __expf(s - 8.0f);
                    lsum[r] += p;
                    pr[c] = (bf16_t)p;
                }
                *(bf16x4*)&Pb[wave][(quad * 4 + r) * 72 + l15 * 4] = pr;
            }
            asm volatile("s_waitcnt lgkmcnt(0)" ::: "memory");  // wave-private LDS RAW

            const bf16x8 ap0 = *(const bf16x8*)&Pb[wave][l15 * 72 + quad * 8];
            const bf16x8 ap1 = *(const bf16x8*)&Pb[wave][l15 * 72 + 32 + quad * 8];
#pragma unroll
            for (int t = 0; t < 4; ++t) {
                const bf16x8 bv0 = *(const bf16x8*)&Vb[buf][(t * 16 + l15) * 64 + swA];
                const bf16x8 bv1 = *(const bf16x8*)&Vb[buf][(t * 16 + l15) * 64 + swB];
                oacc[t] = __builtin_amdgcn_mfma_f32_16x16x32_bf16(ap0, bv0, oacc[t], 0, 0, 0);
                oacc[t] = __builtin_amdgcn_mfma_f32_16x16x32_bf16(ap1, bv1, oacc[t], 0, 0, 0);
            }
        }

        __syncthreads();    // staged buf^1 landed; all waves done reading buf
        buf ^= 1;
    }

    // ---- fused epilogue: 1/l normalize + direct AO bf16 write ----
    const int b = bh >> 4, h = bh & 15;
    float inv[4];
#pragma unroll
    for (int r = 0; r < 4; ++r) {
        float s = lsum[r];
        s += __shfl_xor(s, 1);
        s += __shfl_xor(s, 2);
        s += __shfl_xor(s, 4);
        s += __shfl_xor(s, 8);
        inv[r] = 1.0f / s;
    }
#pragma unroll
    for (int t = 0; t < 4; ++t)
#pragma unroll
        for (int r = 0; r < 4; ++r) {
            const int qa = q0 + quad * 4 + r;
            AO[(size_t)(b * SEQ + qa) * DMODEL + h * 64 + t * 16 + l15] =
                (bf16_t)(oacc[t][r] * inv[r]);
        }
}

extern "C" void kernel_launch(void* const* d_in, const int* in_sizes, int n_in,
                              void* d_out, int out_size, void* d_ws, size_t ws_size,
                              hipStream_t stream) {
    (void)in_sizes; (void)n_in; (void)out_size; (void)ws_size;
    const float* x    = (const float*)d_in[0];
    const int*   pos  = (const int*)d_in[1];
    const float* qkvw = (const float*)d_in[2];
    const float* ow   = (const float*)d_in[3];
    float* out = (float*)d_out;

    const size_t HEAD_ELEMS = (size_t)BATCH * NHEADS * SEQ * DK;  // 4,194,304
    bf16_t* Qw  = (bf16_t*)d_ws;              // 8 MiB
    bf16_t* Kw  = Qw + HEAD_ELEMS;            // 8 MiB
    bf16_t* Vt  = Kw + HEAD_ELEMS;            // 8 MiB (transposed+permuted V)
    bf16_t* AO  = Vt + HEAD_ELEMS;            // 8 MiB — aliased with xb (disjoint live ranges)
    bf16_t* xb  = AO;
    bf16_t* wb  = AO + X_N;                   // 6 MiB
    bf16_t* ob  = wb + W_N;                   // 2 MiB
    f32x2*  tbl = (f32x2*)(ob + O_N);         // 512 KiB RoPE table (~40.5 MiB total)

    // 1) fp32 -> bf16 + RoPE cos/sin table
    convert_kernel<<<dim3(4096 + 256), 256, 0, stream>>>(x, qkvw, ow, pos, xb, wb, ob, tbl);
    // 2) QKV projection (dbuf BK=64) + table RoPE -> Q/K head-major, V^T
    qkv_gemm_kernel<<<dim3(24, 32), 256, 0, stream>>>(xb, wb, tbl, Qw, Kw, Vt);
    // 3) classic flash attention, 8 waves x 16 queries, fused normalize
    attn_kernel<<<dim3(512), 512, 0, stream>>>(Qw, Kw, Vt, AO);
    // 4) output projection (dbuf BK=64, 128x64 tiles) -> fp32 d_out
    out_gemm_kernel<<<dim3(16, 32), 256, 0, stream>>>(AO, ob, out);
}